// Round 8
// baseline (109.368 us; speedup 1.0000x reference)
//
#include <hip/hip_runtime.h>
#include <math.h>

#define N_ATOMS 4096
#define SPECIES 100
#define FEA 64
#define M_NBR 12

typedef unsigned short u16;
typedef __attribute__((ext_vector_type(8))) _Float16 f16x8;
typedef __attribute__((ext_vector_type(4))) float f32x4;

constexpr float LN_EPS = 1e-5f;
constexpr float GAUSS_COEFF = -31.0078125f; // -0.5/(8/63)^2
constexpr float D2_INF = 3.4e38f;

__device__ __forceinline__ float sigmoidf_(float x){ return 1.0f/(1.0f+__expf(-x)); }
__device__ __forceinline__ float softplusf_(float x){
    return fmaxf(x, 0.0f) + log1pf(__expf(-fabsf(x)));
}
__device__ __forceinline__ u16 f16bits(_Float16 h){ return *(u16*)&h; }

// ---------------- setup: fracs transpose + weight fp16 split-pack ----------------
// W[192][128] splits into 3 K=64 blocks: self(0-63), nbr(64-127), gauss(128-191).
// mat = layer*3 + k/64  (0:S1 1:N1 2:G1 3:S2 4:N2 5:G2), each 16KB fp16 in
// per-(ch,nt) wave-contiguous B layout: dest[mat*8192 + ((ch*8+nt)*64+lane)*8 + i]
__global__ __launch_bounds__(256) void k_setup(const float* __restrict__ fracs,
        const float* __restrict__ w1, const float* __restrict__ w2,
        float* __restrict__ fx, float* __restrict__ fy, float* __restrict__ fz,
        u16* __restrict__ wpk){
    int b = blockIdx.x, t = threadIdx.x;
    if (b < 192){
        int gid = b * 256 + t;             // 0..49151
        int layer = gid / 24576;
        int e = gid % 24576;
        int k = e >> 7, n = e & 127;
        float x = (layer ? w2 : w1)[e];
        int mat = layer * 3 + (k >> 6);
        int kk = k & 63;
        int ch = kk >> 5, lg2 = (kk >> 3) & 3, i = kk & 7;
        int nt = n >> 4, lr2 = n & 15;
        int dest = mat * 8192 + ((ch * 8 + nt) * 64 + (lg2 * 16 + lr2)) * 8 + i;
        wpk[dest] = f16bits((_Float16)x);
    } else {
        int j = (b - 192) * 256 + t;
        fx[j] = fracs[j*3+0];
        fy[j] = fracs[j*3+1];
        fz[j] = fracs[j*3+2];
    }
}

// ---------------- embedding: softmax(species_logits) @ emb_w + emb_b ----------------
__global__ __launch_bounds__(256) void k_embed(const float* __restrict__ logits,
        const float* __restrict__ emb_w, const float* __restrict__ emb_b,
        float* __restrict__ atom0, u16* __restrict__ a0f){
    __shared__ float sE[4][SPECIES];
    int tid = threadIdx.x;
    int grp = tid >> 6;
    int f = tid & 63;
    int a = blockIdx.x * 4 + grp;
    const float* lg = logits + (long)a * SPECIES;
    float l0 = lg[f];
    float l1 = (f + 64 < SPECIES) ? lg[f + 64] : -1e30f;
    float mx = fmaxf(l0, l1);
    #pragma unroll
    for (int off = 32; off; off >>= 1) mx = fmaxf(mx, __shfl_xor(mx, off));
    float e0 = __expf(l0 - mx);
    float e1 = (f + 64 < SPECIES) ? __expf(l1 - mx) : 0.0f;
    sE[grp][f] = e0;
    if (f + 64 < SPECIES) sE[grp][64 + f] = e1;
    float sm = e0 + e1;
    #pragma unroll
    for (int off = 32; off; off >>= 1) sm += __shfl_xor(sm, off);
    __syncthreads();
    float acc = 0.0f;
    for (int s = 0; s < SPECIES; ++s) acc += sE[grp][s] * emb_w[s * FEA + f];
    float v = acc / sm + emb_b[f];
    atom0[(long)a * FEA + f] = v;
    a0f[a * FEA + f] = f16bits((_Float16)v);
}

// ---------------- top-12 via histogram threshold + candidate compaction ----------------
__global__ __launch_bounds__(256) void k_topk(const float* __restrict__ fx,
        const float* __restrict__ fy, const float* __restrict__ fz,
        const float* __restrict__ lat, int* __restrict__ nbr_idx,
        float* __restrict__ nbr_dist){
    __shared__ int   hist[256];
    __shared__ int   cnt;
    __shared__ float sThr;
    __shared__ float candD[256];
    __shared__ int   candI[256];
    int i = blockIdx.x, tid = threadIdx.x;
    hist[tid] = 0;
    if (tid == 0) cnt = 0;
    __syncthreads();
    float l00=lat[0],l01=lat[1],l02=lat[2];
    float l10=lat[3],l11=lat[4],l12=lat[5];
    float l20=lat[6],l21=lat[7],l22=lat[8];
    float xi = fx[i], yi = fy[i], zi = fz[i];
    float d2r[16];
    #pragma unroll
    for (int k = 0; k < 16; ++k){
        int j = tid + k * 256;
        float dx = xi - fx[j];
        float dy = yi - fy[j];
        float dz = zi - fz[j];
        dx -= rintf(dx); dy -= rintf(dy); dz -= rintf(dz);
        float cx = dx*l00 + dy*l10 + dz*l20;
        float cy = dx*l01 + dy*l11 + dz*l21;
        float cz = dx*l02 + dy*l12 + dz*l22;
        float d2 = cx*cx + cy*cy + cz*cz;
        if (j == i) d2 = D2_INF;
        d2r[k] = d2;
        if (d2 < 4.0f) atomicAdd(&hist[(int)(d2 * 64.0f)], 1);
    }
    __syncthreads();
    if (tid < 64){
        int s0 = hist[4*tid] + hist[4*tid+1] + hist[4*tid+2] + hist[4*tid+3];
        int sc = s0;
        #pragma unroll
        for (int off = 1; off < 64; off <<= 1){
            int o = __shfl_up(sc, off);
            if (tid >= off) sc += o;
        }
        unsigned long long mball = __ballot(sc >= M_NBR);
        if (mball == 0ULL){
            if (tid == 0) sThr = 1e30f;
        } else {
            int gbin = __ffsll(mball) - 1;
            if (tid == gbin){
                int c = sc - s0;
                float th = 4.0f;
                #pragma unroll
                for (int b = 0; b < 4; ++b){
                    c += hist[4*gbin + b];
                    if (c >= M_NBR){ th = (float)(4*gbin + b + 1) * (1.0f/64.0f); break; }
                }
                sThr = th;
            }
        }
    }
    __syncthreads();
    float thr = sThr;
    #pragma unroll
    for (int k = 0; k < 16; ++k){
        if (d2r[k] < thr){
            int p = atomicAdd(&cnt, 1);
            if (p < 256){ candD[p] = d2r[k]; candI[p] = tid + k * 256; }
        }
    }
    __syncthreads();
    if (tid < 64){
        int n = cnt < 256 ? cnt : 256;
        float v0 = (tid       < n) ? candD[tid]       : D2_INF;
        int   i0 = (tid       < n) ? candI[tid]       : 0x7FFFFFFF;
        float v1 = (tid + 64  < n) ? candD[tid + 64]  : D2_INF;
        int   i1 = (tid + 64  < n) ? candI[tid + 64]  : 0x7FFFFFFF;
        float v2 = (tid + 128 < n) ? candD[tid + 128] : D2_INF;
        int   i2 = (tid + 128 < n) ? candI[tid + 128] : 0x7FFFFFFF;
        float v3 = (tid + 192 < n) ? candD[tid + 192] : D2_INF;
        int   i3 = (tid + 192 < n) ? candI[tid + 192] : 0x7FFFFFFF;
        for (int r = 0; r < M_NBR; ++r){
            float bv = v0; int bi = i0;
            if (v1 < bv || (v1 == bv && i1 < bi)){ bv = v1; bi = i1; }
            if (v2 < bv || (v2 == bv && i2 < bi)){ bv = v2; bi = i2; }
            if (v3 < bv || (v3 == bv && i3 < bi)){ bv = v3; bi = i3; }
            #pragma unroll
            for (int off = 1; off < 64; off <<= 1){
                float ov = __shfl_xor(bv, off);
                int   oi = __shfl_xor(bi, off);
                if (ov < bv || (ov == bv && oi < bi)){ bv = ov; bi = oi; }
            }
            if (i0 == bi) v0 = D2_INF;
            if (i1 == bi) v1 = D2_INF;
            if (i2 == bi) v2 = D2_INF;
            if (i3 == bi) v3 = D2_INF;
            if (tid == 0){
                nbr_idx[i * M_NBR + r]  = bi;
                nbr_dist[i * M_NBR + r] = sqrtf(bv);
            }
        }
    }
}

// ---------------- precompute S1 = a0@Ws1, N1 = a0@Wn1, N2 = a0@Wn2 ----------------
__global__ __launch_bounds__(64) void k_precomp(const u16* __restrict__ a0f,
        const u16* __restrict__ wpk, float* __restrict__ S1,
        float* __restrict__ N1, float* __restrict__ N2){
    const int l = threadIdx.x;
    const int lg = l >> 4, lr = l & 15;
    const int blk = blockIdx.x;
    f16x8 af[2];
    #pragma unroll
    for (int c = 0; c < 2; ++c)
        af[c] = *(const f16x8*)(a0f + (blk * 16 + lr) * 64 + c * 32 + lg * 8);
    const u16* WB[3] = { wpk, wpk + 8192, wpk + 4 * 8192 };   // S1, N1, N2
    float* OUT[3] = { S1, N1, N2 };
    #pragma unroll
    for (int m = 0; m < 3; ++m){
        f32x4 acc[8];
        #pragma unroll
        for (int nt = 0; nt < 8; ++nt) acc[nt] = 0.0f;
        #pragma unroll
        for (int c = 0; c < 2; ++c)
            #pragma unroll
            for (int nt = 0; nt < 8; ++nt){
                const f16x8 b = *(const f16x8*)(WB[m] + ((c * 8 + nt) * 64 + l) * 8);
                acc[nt] = __builtin_amdgcn_mfma_f32_16x16x32_f16(af[c], b, acc[nt], 0, 0, 0);
            }
        #pragma unroll
        for (int nt = 0; nt < 8; ++nt)
            #pragma unroll
            for (int rr = 0; rr < 4; ++rr)
                OUT[m][(blk * 16 + lg * 4 + rr) * 128 + nt * 16 + lr] = acc[nt][rr];
    }
}

// ---------------- fused CGCNN layers 1+2 (gaussian MFMA; S/N staged via LDS) --------
// Block = 192 threads (3 waves x 16 rows) = 48 rows = 4 atoms; grid 1024.
// nbuf[row][c] holds (N + S + bias) built from coalesced float4 gathers.
__global__ __launch_bounds__(192) void k_fused(
        const float* __restrict__ atom0F,
        const int* __restrict__ nbr_idx, const float* __restrict__ nbr_dist,
        const float* __restrict__ S1g, const float* __restrict__ N1g,
        const float* __restrict__ N2g, const u16* __restrict__ wpk,
        const float* __restrict__ b1, const float* __restrict__ g1, const float* __restrict__ be1,
        const float* __restrict__ b2, const float* __restrict__ g2, const float* __restrict__ be2,
        float* __restrict__ outF)
{
    __shared__ float nbuf[48][132];  // 25.3KB  (N + S + bias), reused per layer
    __shared__ float prod[48][68];   // 13.1KB
    __shared__ float sSF[4][64];     // layer-1 out f32 (residual)
    __shared__ u16   sSH[4][64];     // layer-1 out fp16 (A-frags for S2)
    __shared__ float sS2[4][132];    // S2 = atom1 @ Ws2
    __shared__ int   sNid[48];
    __shared__ float sDist[48];

    const int t = threadIdx.x;
    const int w = t >> 6, l = t & 63;
    const int lg = l >> 4, lr = l & 15;
    const int blk = blockIdx.x;

    if (t < 48){
        sNid[t]  = nbr_idx[blk * 48 + t];
        sDist[t] = nbr_dist[blk * 48 + t];
    }
    __syncthreads();

    // cooperative: nbuf[row][c] = N1[nid[row]][c] + S1[atom(row)][c] + b1[c]
    #pragma unroll
    for (int it = 0; it < 8; ++it){
        int idx = it * 192 + t;
        int row = idx >> 5, c4 = (idx & 31) << 2;
        float4 nv = *(const float4*)(N1g + (long)sNid[row] * 128 + c4);
        float4 sv = *(const float4*)(S1g + (long)(blk * 4 + row / 12) * 128 + c4);
        float4 bb = *(const float4*)(b1 + c4);
        float4 r;
        r.x = nv.x + sv.x + bb.x; r.y = nv.y + sv.y + bb.y;
        r.z = nv.z + sv.z + bb.z; r.w = nv.w + sv.w + bb.w;
        *(float4*)(&nbuf[row][c4]) = r;
    }

    // gaussian A-fragments (A row = lr), shared by both layers
    const float dist = sDist[w * 16 + lr];
    f16x8 ga[2];
    #pragma unroll
    for (int c = 0; c < 2; ++c)
        #pragma unroll
        for (int i = 0; i < 8; ++i){
            int k = c * 32 + lg * 8 + i;
            float dd = dist - (float)k * (8.0f / 63.0f);
            ga[c][i] = (_Float16)__expf(GAUSS_COEFF * dd * dd);
        }

    const u16* wg1 = wpk + 2 * 8192;
    const u16* ws2 = wpk + 3 * 8192;
    const u16* wg2 = wpk + 5 * 8192;

    // layer-1 gaussian MFMA
    f32x4 acc[8];
    #pragma unroll
    for (int nt = 0; nt < 8; ++nt) acc[nt] = 0.0f;
    #pragma unroll
    for (int c = 0; c < 2; ++c)
        #pragma unroll
        for (int nt = 0; nt < 8; ++nt){
            const f16x8 b = *(const f16x8*)(wg1 + ((c * 8 + nt) * 64 + l) * 8);
            acc[nt] = __builtin_amdgcn_mfma_f32_16x16x32_f16(ga[c], b, acc[nt], 0, 0, 0);
        }

    __syncthreads();   // nbuf1 ready

    // z1 = acc + nbuf1 (in place)
    #pragma unroll
    for (int nt = 0; nt < 8; ++nt)
        #pragma unroll
        for (int rr = 0; rr < 4; ++rr)
            acc[nt][rr] += nbuf[w * 16 + lg * 4 + rr][nt * 16 + lr];

    // issue N2 gathers early (consumed after S2 mini-GEMM)
    float4 n2r[8];
    #pragma unroll
    for (int it = 0; it < 8; ++it){
        int idx = it * 192 + t;
        int row = idx >> 5, c4 = (idx & 31) << 2;
        n2r[it] = *(const float4*)(N2g + (long)sNid[row] * 128 + c4);
    }

    // layer-2 gaussian MFMA (independent of layer-1 results; overlaps N2 loads)
    f32x4 acc2[8];
    #pragma unroll
    for (int nt = 0; nt < 8; ++nt) acc2[nt] = 0.0f;
    #pragma unroll
    for (int c = 0; c < 2; ++c)
        #pragma unroll
        for (int nt = 0; nt < 8; ++nt){
            const f16x8 b = *(const f16x8*)(wg2 + ((c * 8 + nt) * 64 + l) * 8);
            acc2[nt] = __builtin_amdgcn_mfma_f32_16x16x32_f16(ga[c], b, acc2[nt], 0, 0, 0);
        }

    // LN1 + products
    {
        float s[4] = {0,0,0,0}, q[4] = {0,0,0,0};
        #pragma unroll
        for (int nt = 0; nt < 8; ++nt)
            #pragma unroll
            for (int rr = 0; rr < 4; ++rr){
                float v = acc[nt][rr];
                s[rr] += v; q[rr] += v * v;
            }
        #pragma unroll
        for (int rr = 0; rr < 4; ++rr){
            #pragma unroll
            for (int m = 1; m < 16; m <<= 1){
                s[rr] += __shfl_xor(s[rr], m);
                q[rr] += __shfl_xor(q[rr], m);
            }
        }
        #pragma unroll
        for (int rr = 0; rr < 4; ++rr){
            float mean = s[rr] * (1.0f / 128.0f);
            float var  = q[rr] * (1.0f / 128.0f) - mean * mean;
            float inv  = rsqrtf(var + LN_EPS);
            #pragma unroll
            for (int nt = 0; nt < 4; ++nt){
                int cf = nt * 16 + lr, cc = cf + 64;
                float zf = (acc[nt][rr]     - mean) * inv * g1[cf] + be1[cf];
                float zc = (acc[nt + 4][rr] - mean) * inv * g1[cc] + be1[cc];
                prod[w * 16 + lg * 4 + rr][cf] = sigmoidf_(zf) * softplusf_(zc);
            }
        }
    }
    __syncthreads();

    // epilogue 1: per-atom reduce 12 rows + residual + softplus -> sSF/sSH
    if (t < 64){
        int a_ = t >> 4, c0 = (t & 15) * 4;
        float4 sm = make_float4(0, 0, 0, 0);
        #pragma unroll
        for (int m = 0; m < 12; ++m){
            const float4 pv = *(const float4*)&prod[a_ * 12 + m][c0];
            sm.x += pv.x; sm.y += pv.y; sm.z += pv.z; sm.w += pv.w;
        }
        int atom = blk * 4 + a_;
        const float4 sf = *(const float4*)(atom0F + (long)atom * 64 + c0);
        float o0 = softplusf_(sf.x + sm.x);
        float o1 = softplusf_(sf.y + sm.y);
        float o2 = softplusf_(sf.z + sm.z);
        float o3 = softplusf_(sf.w + sm.w);
        *(float4*)(&sSF[a_][c0]) = make_float4(o0, o1, o2, o3);
        ushort4 hv;
        hv.x = f16bits((_Float16)o0); hv.y = f16bits((_Float16)o1);
        hv.z = f16bits((_Float16)o2); hv.w = f16bits((_Float16)o3);
        *(ushort4*)(&sSH[a_][c0]) = hv;
    }
    __syncthreads();

    // S2 mini-GEMM (wave 0): S2[a][c] = atom1[a][:] @ Ws2
    if (t < 64){
        f16x8 af[2];
        #pragma unroll
        for (int c = 0; c < 2; ++c){
            if (lr < 4) af[c] = *(const f16x8*)(&sSH[lr][c * 32 + lg * 8]);
            else        af[c] = 0;
        }
        f32x4 a2[8];
        #pragma unroll
        for (int nt = 0; nt < 8; ++nt) a2[nt] = 0.0f;
        #pragma unroll
        for (int c = 0; c < 2; ++c)
            #pragma unroll
            for (int nt = 0; nt < 8; ++nt){
                const f16x8 b = *(const f16x8*)(ws2 + ((c * 8 + nt) * 64 + l) * 8);
                a2[nt] = __builtin_amdgcn_mfma_f32_16x16x32_f16(af[c], b, a2[nt], 0, 0, 0);
            }
        if (lg == 0){
            #pragma unroll
            for (int nt = 0; nt < 8; ++nt)
                #pragma unroll
                for (int rr = 0; rr < 4; ++rr)
                    sS2[rr][nt * 16 + lr] = a2[nt][rr];
        }
    }
    __syncthreads();

    // nbuf2[row][c] = N2(reg) + S2 + b2
    #pragma unroll
    for (int it = 0; it < 8; ++it){
        int idx = it * 192 + t;
        int row = idx >> 5, c4 = (idx & 31) << 2;
        float4 s2v = *(const float4*)(&sS2[row / 12][c4]);
        float4 bb = *(const float4*)(b2 + c4);
        float4 r;
        r.x = n2r[it].x + s2v.x + bb.x; r.y = n2r[it].y + s2v.y + bb.y;
        r.z = n2r[it].z + s2v.z + bb.z; r.w = n2r[it].w + s2v.w + bb.w;
        *(float4*)(&nbuf[row][c4]) = r;
    }
    __syncthreads();

    // z2 = acc2 + nbuf2
    #pragma unroll
    for (int nt = 0; nt < 8; ++nt)
        #pragma unroll
        for (int rr = 0; rr < 4; ++rr)
            acc2[nt][rr] += nbuf[w * 16 + lg * 4 + rr][nt * 16 + lr];

    // LN2 + products
    {
        float s[4] = {0,0,0,0}, q[4] = {0,0,0,0};
        #pragma unroll
        for (int nt = 0; nt < 8; ++nt)
            #pragma unroll
            for (int rr = 0; rr < 4; ++rr){
                float v = acc2[nt][rr];
                s[rr] += v; q[rr] += v * v;
            }
        #pragma unroll
        for (int rr = 0; rr < 4; ++rr){
            #pragma unroll
            for (int m = 1; m < 16; m <<= 1){
                s[rr] += __shfl_xor(s[rr], m);
                q[rr] += __shfl_xor(q[rr], m);
            }
        }
        #pragma unroll
        for (int rr = 0; rr < 4; ++rr){
            float mean = s[rr] * (1.0f / 128.0f);
            float var  = q[rr] * (1.0f / 128.0f) - mean * mean;
            float inv  = rsqrtf(var + LN_EPS);
            #pragma unroll
            for (int nt = 0; nt < 4; ++nt){
                int cf = nt * 16 + lr, cc = cf + 64;
                float zf = (acc2[nt][rr]     - mean) * inv * g2[cf] + be2[cf];
                float zc = (acc2[nt + 4][rr] - mean) * inv * g2[cc] + be2[cc];
                prod[w * 16 + lg * 4 + rr][cf] = sigmoidf_(zf) * softplusf_(zc);
            }
        }
    }
    __syncthreads();

    // epilogue 2 -> outF
    if (t < 64){
        int a_ = t >> 4, c0 = (t & 15) * 4;
        float4 sm = make_float4(0, 0, 0, 0);
        #pragma unroll
        for (int m = 0; m < 12; ++m){
            const float4 pv = *(const float4*)&prod[a_ * 12 + m][c0];
            sm.x += pv.x; sm.y += pv.y; sm.z += pv.z; sm.w += pv.w;
        }
        int atom = blk * 4 + a_;
        const float4 sf = *(const float4*)(&sSF[a_][c0]);
        float o0 = softplusf_(sf.x + sm.x);
        float o1 = softplusf_(sf.y + sm.y);
        float o2 = softplusf_(sf.z + sm.z);
        float o3 = softplusf_(sf.w + sm.w);
        *(float4*)(outF + (long)atom * 64 + c0) = make_float4(o0, o1, o2, o3);
    }
}

// ---------------- pooling: deterministic two-stage tree ----------------
__global__ __launch_bounds__(256) void k_partial(const float* __restrict__ atom,
        const float* __restrict__ occ, float* __restrict__ partials){
    int b = blockIdx.x, tid = threadIdx.x;
    int f = tid & 63, sub = tid >> 6;
    __shared__ float sAcc[256];
    float acc = 0.0f;
    for (int it = 0; it < 16; ++it){
        int a = b * 64 + sub + it * 4;
        float p = sigmoidf_(occ[a]);
        acc += atom[(long)a * FEA + f] * p;
    }
    sAcc[tid] = acc;
    __syncthreads();
    if (tid < 64){
        float s = sAcc[f] + sAcc[64 + f] + sAcc[128 + f] + sAcc[192 + f];
        partials[b * 65 + f] = s;
        float po = sigmoidf_(occ[b * 64 + f]);
        #pragma unroll
        for (int off = 32; off; off >>= 1) po += __shfl_down(po, off);
        if (f == 0) partials[b * 65 + 64] = po;
    }
}

__global__ __launch_bounds__(64) void k_final(const float* __restrict__ partials,
        const float* __restrict__ fc_w, const float* __restrict__ fc_b,
        float* __restrict__ out){
    int f = threadIdx.x;
    float num = 0.0f;
    for (int p = 0; p < 64; ++p) num += partials[p * 65 + f];
    float occs = partials[f * 65 + 64];
    #pragma unroll
    for (int off = 32; off; off >>= 1) occs += __shfl_down(occs, off);
    occs = __shfl(occs, 0);
    float gf = num / (occs + 1e-6f);
    float v = gf * fc_w[f];
    #pragma unroll
    for (int off = 32; off; off >>= 1) v += __shfl_down(v, off);
    if (f == 0) out[0] = v + fc_b[0];
}

extern "C" void kernel_launch(void* const* d_in, const int* in_sizes, int n_in,
                              void* d_out, int out_size, void* d_ws, size_t ws_size,
                              hipStream_t stream) {
    const float* lat    = (const float*)d_in[0];
    const float* fracs  = (const float*)d_in[1];
    const float* slog   = (const float*)d_in[2];
    const float* occ    = (const float*)d_in[3];
    const float* emb_w  = (const float*)d_in[4];
    const float* emb_b  = (const float*)d_in[5];
    const float* w1     = (const float*)d_in[6];
    const float* b1     = (const float*)d_in[7];
    const float* g1     = (const float*)d_in[8];
    const float* be1    = (const float*)d_in[9];
    const float* w2     = (const float*)d_in[10];
    const float* b2     = (const float*)d_in[11];
    const float* g2     = (const float*)d_in[12];
    const float* be2    = (const float*)d_in[13];
    const float* fc_w   = (const float*)d_in[14];
    const float* fc_b   = (const float*)d_in[15];
    float* out = (float*)d_out;

    char* ws = (char*)d_ws;
    auto alloc = [&](size_t bytes) -> void* {
        void* p = (void*)ws;
        ws += (bytes + 255) & ~(size_t)255;
        return p;
    };
    int*   nbr_idx  = (int*)  alloc((size_t)N_ATOMS * M_NBR * 4);
    float* nbr_dist = (float*)alloc((size_t)N_ATOMS * M_NBR * 4);
    float* atom0    = (float*)alloc((size_t)N_ATOMS * FEA * 4);
    float* atom1    = (float*)alloc((size_t)N_ATOMS * FEA * 4);
    u16*   a0f      = (u16*)  alloc((size_t)N_ATOMS * FEA * 2);
    u16*   wpk      = (u16*)  alloc((size_t)6 * 8192 * 2);
    float* S1       = (float*)alloc((size_t)N_ATOMS * 128 * 4);
    float* N1       = (float*)alloc((size_t)N_ATOMS * 128 * 4);
    float* N2       = (float*)alloc((size_t)N_ATOMS * 128 * 4);
    float* fxa      = (float*)alloc((size_t)N_ATOMS * 4);
    float* fya      = (float*)alloc((size_t)N_ATOMS * 4);
    float* fza      = (float*)alloc((size_t)N_ATOMS * 4);
    float* partials = (float*)alloc((size_t)64 * 65 * 4);

    k_setup  <<<208, 256, 0, stream>>>(fracs, w1, w2, fxa, fya, fza, wpk);
    k_embed  <<<N_ATOMS / 4, 256, 0, stream>>>(slog, emb_w, emb_b, atom0, a0f);
    k_topk   <<<N_ATOMS, 256, 0, stream>>>(fxa, fya, fza, lat, nbr_idx, nbr_dist);
    k_precomp<<<N_ATOMS / 16, 64, 0, stream>>>(a0f, wpk, S1, N1, N2);
    k_fused  <<<N_ATOMS / 4, 192, 0, stream>>>(atom0, nbr_idx, nbr_dist, S1, N1, N2,
                wpk, b1, g1, be1, b2, g2, be2, atom1);
    k_partial<<<64, 256, 0, stream>>>(atom1, occ, partials);
    k_final  <<<1, 64, 0, stream>>>(partials, fc_w, fc_b, out);
}

// Round 9
// 96.003 us; speedup vs baseline: 1.1392x; 1.1392x over previous
//
#include <hip/hip_runtime.h>
#include <math.h>

#define N_ATOMS 4096
#define SPECIES 100
#define FEA 64
#define M_NBR 12

typedef unsigned short u16;
typedef __attribute__((ext_vector_type(8))) _Float16 f16x8;
typedef __attribute__((ext_vector_type(4))) float f32x4;

constexpr float LN_EPS = 1e-5f;
constexpr float GAUSS_COEFF = -31.0078125f; // -0.5/(8/63)^2
constexpr float D2_INF = 3.4e38f;

__device__ __forceinline__ float sigmoidf_(float x){ return 1.0f/(1.0f+__expf(-x)); }
__device__ __forceinline__ float softplusf_(float x){
    return fmaxf(x, 0.0f) + log1pf(__expf(-fabsf(x)));
}
__device__ __forceinline__ u16 f16bits(_Float16 h){ return *(u16*)&h; }

// ---------------- setup: fracs transpose + weight fp16 split-pack ----------------
// W[192][128] splits into 3 K=64 blocks: self(0-63), nbr(64-127), gauss(128-191).
// mat = layer*3 + k/64  (0:S1 1:N1 2:G1 3:S2 4:N2 5:G2), each 16KB fp16 in
// per-(ch,nt) wave-contiguous B layout: dest[mat*8192 + ((ch*8+nt)*64+lane)*8 + i]
__global__ __launch_bounds__(256) void k_setup(const float* __restrict__ fracs,
        const float* __restrict__ w1, const float* __restrict__ w2,
        float* __restrict__ fx, float* __restrict__ fy, float* __restrict__ fz,
        u16* __restrict__ wpk){
    int b = blockIdx.x, t = threadIdx.x;
    if (b < 192){
        int gid = b * 256 + t;             // 0..49151
        int layer = gid / 24576;
        int e = gid % 24576;
        int k = e >> 7, n = e & 127;
        float x = (layer ? w2 : w1)[e];
        int mat = layer * 3 + (k >> 6);
        int kk = k & 63;
        int ch = kk >> 5, lg2 = (kk >> 3) & 3, i = kk & 7;
        int nt = n >> 4, lr2 = n & 15;
        int dest = mat * 8192 + ((ch * 8 + nt) * 64 + (lg2 * 16 + lr2)) * 8 + i;
        wpk[dest] = f16bits((_Float16)x);
    } else {
        int j = (b - 192) * 256 + t;
        fx[j] = fracs[j*3+0];
        fy[j] = fracs[j*3+1];
        fz[j] = fracs[j*3+2];
    }
}

// ---------------- embedding: softmax(species_logits) @ emb_w + emb_b ----------------
__global__ __launch_bounds__(256) void k_embed(const float* __restrict__ logits,
        const float* __restrict__ emb_w, const float* __restrict__ emb_b,
        float* __restrict__ atom0, u16* __restrict__ a0f){
    __shared__ float sE[4][SPECIES];
    int tid = threadIdx.x;
    int grp = tid >> 6;
    int f = tid & 63;
    int a = blockIdx.x * 4 + grp;
    const float* lg = logits + (long)a * SPECIES;
    float l0 = lg[f];
    float l1 = (f + 64 < SPECIES) ? lg[f + 64] : -1e30f;
    float mx = fmaxf(l0, l1);
    #pragma unroll
    for (int off = 32; off; off >>= 1) mx = fmaxf(mx, __shfl_xor(mx, off));
    float e0 = __expf(l0 - mx);
    float e1 = (f + 64 < SPECIES) ? __expf(l1 - mx) : 0.0f;
    sE[grp][f] = e0;
    if (f + 64 < SPECIES) sE[grp][64 + f] = e1;
    float sm = e0 + e1;
    #pragma unroll
    for (int off = 32; off; off >>= 1) sm += __shfl_xor(sm, off);
    __syncthreads();
    float acc = 0.0f;
    for (int s = 0; s < SPECIES; ++s) acc += sE[grp][s] * emb_w[s * FEA + f];
    float v = acc / sm + emb_b[f];
    atom0[(long)a * FEA + f] = v;
    a0f[a * FEA + f] = f16bits((_Float16)v);
}

// ---------------- top-12 via histogram threshold + candidate compaction ----------------
__global__ __launch_bounds__(256) void k_topk(const float* __restrict__ fx,
        const float* __restrict__ fy, const float* __restrict__ fz,
        const float* __restrict__ lat, int* __restrict__ nbr_idx,
        float* __restrict__ nbr_dist){
    __shared__ int   hist[256];
    __shared__ int   cnt;
    __shared__ float sThr;
    __shared__ float candD[256];
    __shared__ int   candI[256];
    int i = blockIdx.x, tid = threadIdx.x;
    hist[tid] = 0;
    if (tid == 0) cnt = 0;
    __syncthreads();
    float l00=lat[0],l01=lat[1],l02=lat[2];
    float l10=lat[3],l11=lat[4],l12=lat[5];
    float l20=lat[6],l21=lat[7],l22=lat[8];
    float xi = fx[i], yi = fy[i], zi = fz[i];
    float d2r[16];
    #pragma unroll
    for (int k = 0; k < 16; ++k){
        int j = tid + k * 256;
        float dx = xi - fx[j];
        float dy = yi - fy[j];
        float dz = zi - fz[j];
        dx -= rintf(dx); dy -= rintf(dy); dz -= rintf(dz);
        float cx = dx*l00 + dy*l10 + dz*l20;
        float cy = dx*l01 + dy*l11 + dz*l21;
        float cz = dx*l02 + dy*l12 + dz*l22;
        float d2 = cx*cx + cy*cy + cz*cz;
        if (j == i) d2 = D2_INF;
        d2r[k] = d2;
        if (d2 < 4.0f) atomicAdd(&hist[(int)(d2 * 64.0f)], 1);
    }
    __syncthreads();
    if (tid < 64){
        int s0 = hist[4*tid] + hist[4*tid+1] + hist[4*tid+2] + hist[4*tid+3];
        int sc = s0;
        #pragma unroll
        for (int off = 1; off < 64; off <<= 1){
            int o = __shfl_up(sc, off);
            if (tid >= off) sc += o;
        }
        unsigned long long mball = __ballot(sc >= M_NBR);
        if (mball == 0ULL){
            if (tid == 0) sThr = 1e30f;
        } else {
            int gbin = __ffsll(mball) - 1;
            if (tid == gbin){
                int c = sc - s0;
                float th = 4.0f;
                #pragma unroll
                for (int b = 0; b < 4; ++b){
                    c += hist[4*gbin + b];
                    if (c >= M_NBR){ th = (float)(4*gbin + b + 1) * (1.0f/64.0f); break; }
                }
                sThr = th;
            }
        }
    }
    __syncthreads();
    float thr = sThr;
    #pragma unroll
    for (int k = 0; k < 16; ++k){
        if (d2r[k] < thr){
            int p = atomicAdd(&cnt, 1);
            if (p < 256){ candD[p] = d2r[k]; candI[p] = tid + k * 256; }
        }
    }
    __syncthreads();
    if (tid < 64){
        int n = cnt < 256 ? cnt : 256;
        float v0 = (tid       < n) ? candD[tid]       : D2_INF;
        int   i0 = (tid       < n) ? candI[tid]       : 0x7FFFFFFF;
        float v1 = (tid + 64  < n) ? candD[tid + 64]  : D2_INF;
        int   i1 = (tid + 64  < n) ? candI[tid + 64]  : 0x7FFFFFFF;
        float v2 = (tid + 128 < n) ? candD[tid + 128] : D2_INF;
        int   i2 = (tid + 128 < n) ? candI[tid + 128] : 0x7FFFFFFF;
        float v3 = (tid + 192 < n) ? candD[tid + 192] : D2_INF;
        int   i3 = (tid + 192 < n) ? candI[tid + 192] : 0x7FFFFFFF;
        for (int r = 0; r < M_NBR; ++r){
            float bv = v0; int bi = i0;
            if (v1 < bv || (v1 == bv && i1 < bi)){ bv = v1; bi = i1; }
            if (v2 < bv || (v2 == bv && i2 < bi)){ bv = v2; bi = i2; }
            if (v3 < bv || (v3 == bv && i3 < bi)){ bv = v3; bi = i3; }
            #pragma unroll
            for (int off = 1; off < 64; off <<= 1){
                float ov = __shfl_xor(bv, off);
                int   oi = __shfl_xor(bi, off);
                if (ov < bv || (ov == bv && oi < bi)){ bv = ov; bi = oi; }
            }
            if (i0 == bi) v0 = D2_INF;
            if (i1 == bi) v1 = D2_INF;
            if (i2 == bi) v2 = D2_INF;
            if (i3 == bi) v3 = D2_INF;
            if (tid == 0){
                nbr_idx[i * M_NBR + r]  = bi;
                nbr_dist[i * M_NBR + r] = sqrtf(bv);
            }
        }
    }
}

// ---------------- precompute S1 = a0f @ Ws1 + b1  (bias folded) ----------------
__global__ __launch_bounds__(64) void k_precomp(const u16* __restrict__ a0f,
        const u16* __restrict__ wpk, const float* __restrict__ b1,
        float* __restrict__ S1){
    const int l = threadIdx.x;
    const int lg = l >> 4, lr = l & 15;
    const int blk = blockIdx.x;
    f16x8 af[2];
    #pragma unroll
    for (int c = 0; c < 2; ++c)
        af[c] = *(const f16x8*)(a0f + (blk * 16 + lr) * 64 + c * 32 + lg * 8);
    f32x4 acc[8];
    #pragma unroll
    for (int nt = 0; nt < 8; ++nt) acc[nt] = 0.0f;
    #pragma unroll
    for (int c = 0; c < 2; ++c)
        #pragma unroll
        for (int nt = 0; nt < 8; ++nt){
            const f16x8 b = *(const f16x8*)(wpk + ((c * 8 + nt) * 64 + l) * 8);
            acc[nt] = __builtin_amdgcn_mfma_f32_16x16x32_f16(af[c], b, acc[nt], 0, 0, 0);
        }
    #pragma unroll
    for (int nt = 0; nt < 8; ++nt)
        #pragma unroll
        for (int rr = 0; rr < 4; ++rr)
            S1[(blk * 16 + lg * 4 + rr) * 128 + nt * 16 + lr] = acc[nt][rr] + b1[nt * 16 + lr];
}

// ---------------- fused CGCNN layers 1+2 ----------------
// Block = 192 thr (3 waves x 16 rows) = 48 rows = 4 atoms; grid 1024 (12 waves/CU).
// Per wave: nbr part via MFMA on gathered a0f rows (128B/edge random traffic),
// gauss part via MFMA; self part gathered from precomputed S1 (block-local).
// nbr/gauss A-fragments reused by layer 2 (B matrices swap).
__global__ __launch_bounds__(192) void k_fused(
        const float* __restrict__ atom0F, const u16* __restrict__ a0f,
        const int* __restrict__ nbr_idx, const float* __restrict__ nbr_dist,
        const float* __restrict__ S1g, const u16* __restrict__ wpk,
        const float* __restrict__ g1, const float* __restrict__ be1,
        const float* __restrict__ b2, const float* __restrict__ g2,
        const float* __restrict__ be2, float* __restrict__ outF)
{
    __shared__ float sS1[4][132];    // S1 (+b1) for the block's 4 atoms
    __shared__ float prod[48][68];
    __shared__ float sSF[4][64];     // layer-1 out f32 (residual)
    __shared__ u16   sSH[4][64];     // layer-1 out fp16 (A-frags for S2)
    __shared__ float sS2[4][132];    // S2 (+b2)

    const int t = threadIdx.x;
    const int w = t >> 6, l = t & 63;
    const int lg = l >> 4, lr = l & 15;
    const int blk = blockIdx.x;
    const int row = blk * 48 + w * 16 + lr;

    // issue the random nbr gather ASAP (the only latency-critical loads)
    const int nid = nbr_idx[row];
    f16x8 nfr[2];
    nfr[0] = *(const f16x8*)(a0f + nid * 64 + lg * 8);
    nfr[1] = *(const f16x8*)(a0f + nid * 64 + 32 + lg * 8);

    // stage S1 rows for the 4 atoms (contiguous, L2-hot)
    if (t < 128){
        int a_ = t >> 5, c4 = (t & 31) << 2;
        *(float4*)(&sS1[a_][c4]) = *(const float4*)(S1g + (long)(blk * 4 + a_) * 128 + c4);
    }

    // gaussian A-fragments (VALU work overlapping the gathers)
    const float dist = nbr_dist[row];
    f16x8 ga[2];
    #pragma unroll
    for (int c = 0; c < 2; ++c)
        #pragma unroll
        for (int i = 0; i < 8; ++i){
            int k = c * 32 + lg * 8 + i;
            float dd = dist - (float)k * (8.0f / 63.0f);
            ga[c][i] = (_Float16)__expf(GAUSS_COEFF * dd * dd);
        }

    // z-row -> local atom mapping (C rows: lg*4+rr)
    int aloc[4];
    #pragma unroll
    for (int rr = 0; rr < 4; ++rr)
        aloc[rr] = (w * 16 + lg * 4 + rr) / 12;

    const u16* wn1 = wpk + 1 * 8192;
    const u16* wg1 = wpk + 2 * 8192;
    const u16* ws2 = wpk + 3 * 8192;
    const u16* wn2 = wpk + 4 * 8192;
    const u16* wg2 = wpk + 5 * 8192;

    // ---- layer 1 MFMA: nbr + gauss ----
    f32x4 acc[8];
    #pragma unroll
    for (int nt = 0; nt < 8; ++nt) acc[nt] = 0.0f;
    #pragma unroll
    for (int c = 0; c < 2; ++c)
        #pragma unroll
        for (int nt = 0; nt < 8; ++nt){
            const f16x8 bn = *(const f16x8*)(wn1 + ((c * 8 + nt) * 64 + l) * 8);
            acc[nt] = __builtin_amdgcn_mfma_f32_16x16x32_f16(nfr[c], bn, acc[nt], 0, 0, 0);
            const f16x8 bg = *(const f16x8*)(wg1 + ((c * 8 + nt) * 64 + l) * 8);
            acc[nt] = __builtin_amdgcn_mfma_f32_16x16x32_f16(ga[c], bg, acc[nt], 0, 0, 0);
        }
    __syncthreads();   // sS1 staged

    // z1 = acc + S1(+b1); LN1; products
    {
        float s[4] = {0,0,0,0}, q[4] = {0,0,0,0};
        #pragma unroll
        for (int nt = 0; nt < 8; ++nt)
            #pragma unroll
            for (int rr = 0; rr < 4; ++rr){
                float v = acc[nt][rr] + sS1[aloc[rr]][nt * 16 + lr];
                acc[nt][rr] = v;
                s[rr] += v; q[rr] += v * v;
            }
        #pragma unroll
        for (int rr = 0; rr < 4; ++rr){
            #pragma unroll
            for (int m = 1; m < 16; m <<= 1){
                s[rr] += __shfl_xor(s[rr], m);
                q[rr] += __shfl_xor(q[rr], m);
            }
        }
        #pragma unroll
        for (int rr = 0; rr < 4; ++rr){
            float mean = s[rr] * (1.0f / 128.0f);
            float var  = q[rr] * (1.0f / 128.0f) - mean * mean;
            float inv  = rsqrtf(var + LN_EPS);
            #pragma unroll
            for (int nt = 0; nt < 4; ++nt){
                int cf = nt * 16 + lr, cc = cf + 64;
                float zf = (acc[nt][rr]     - mean) * inv * g1[cf] + be1[cf];
                float zc = (acc[nt + 4][rr] - mean) * inv * g1[cc] + be1[cc];
                prod[w * 16 + lg * 4 + rr][cf] = sigmoidf_(zf) * softplusf_(zc);
            }
        }
    }
    __syncthreads();

    // epilogue 1: per-atom reduce 12 rows + residual + softplus -> sSF/sSH
    if (t < 64){
        int a_ = t >> 4, c0 = (t & 15) * 4;
        float4 sm = make_float4(0, 0, 0, 0);
        #pragma unroll
        for (int m = 0; m < 12; ++m){
            const float4 pv = *(const float4*)&prod[a_ * 12 + m][c0];
            sm.x += pv.x; sm.y += pv.y; sm.z += pv.z; sm.w += pv.w;
        }
        int atom = blk * 4 + a_;
        const float4 sf = *(const float4*)(atom0F + (long)atom * 64 + c0);
        float o0 = softplusf_(sf.x + sm.x);
        float o1 = softplusf_(sf.y + sm.y);
        float o2 = softplusf_(sf.z + sm.z);
        float o3 = softplusf_(sf.w + sm.w);
        *(float4*)(&sSF[a_][c0]) = make_float4(o0, o1, o2, o3);
        ushort4 hv;
        hv.x = f16bits((_Float16)o0); hv.y = f16bits((_Float16)o1);
        hv.z = f16bits((_Float16)o2); hv.w = f16bits((_Float16)o3);
        *(ushort4*)(&sSH[a_][c0]) = hv;
    }
    __syncthreads();

    // S2 mini-GEMM (wave 0): sS2[a][c] = atom1[a][:] @ Ws2 + b2[c]
    if (t < 64){
        f16x8 af[2];
        #pragma unroll
        for (int c = 0; c < 2; ++c){
            if (lr < 4) af[c] = *(const f16x8*)(&sSH[lr][c * 32 + lg * 8]);
            else        af[c] = 0;
        }
        f32x4 a2[8];
        #pragma unroll
        for (int nt = 0; nt < 8; ++nt) a2[nt] = 0.0f;
        #pragma unroll
        for (int c = 0; c < 2; ++c)
            #pragma unroll
            for (int nt = 0; nt < 8; ++nt){
                const f16x8 b = *(const f16x8*)(ws2 + ((c * 8 + nt) * 64 + l) * 8);
                a2[nt] = __builtin_amdgcn_mfma_f32_16x16x32_f16(af[c], b, a2[nt], 0, 0, 0);
            }
        if (lg == 0){
            #pragma unroll
            for (int nt = 0; nt < 8; ++nt)
                #pragma unroll
                for (int rr = 0; rr < 4; ++rr)
                    sS2[rr][nt * 16 + lr] = a2[nt][rr] + b2[nt * 16 + lr];
        }
    }

    // ---- layer 2 MFMA: nbr + gauss (fragments reused, B swapped) ----
    f32x4 acc2[8];
    #pragma unroll
    for (int nt = 0; nt < 8; ++nt) acc2[nt] = 0.0f;
    #pragma unroll
    for (int c = 0; c < 2; ++c)
        #pragma unroll
        for (int nt = 0; nt < 8; ++nt){
            const f16x8 bn = *(const f16x8*)(wn2 + ((c * 8 + nt) * 64 + l) * 8);
            acc2[nt] = __builtin_amdgcn_mfma_f32_16x16x32_f16(nfr[c], bn, acc2[nt], 0, 0, 0);
            const f16x8 bg = *(const f16x8*)(wg2 + ((c * 8 + nt) * 64 + l) * 8);
            acc2[nt] = __builtin_amdgcn_mfma_f32_16x16x32_f16(ga[c], bg, acc2[nt], 0, 0, 0);
        }
    __syncthreads();   // sS2 ready

    // z2 = acc2 + S2(+b2); LN2; products
    {
        float s[4] = {0,0,0,0}, q[4] = {0,0,0,0};
        #pragma unroll
        for (int nt = 0; nt < 8; ++nt)
            #pragma unroll
            for (int rr = 0; rr < 4; ++rr){
                float v = acc2[nt][rr] + sS2[aloc[rr]][nt * 16 + lr];
                acc2[nt][rr] = v;
                s[rr] += v; q[rr] += v * v;
            }
        #pragma unroll
        for (int rr = 0; rr < 4; ++rr){
            #pragma unroll
            for (int m = 1; m < 16; m <<= 1){
                s[rr] += __shfl_xor(s[rr], m);
                q[rr] += __shfl_xor(q[rr], m);
            }
        }
        #pragma unroll
        for (int rr = 0; rr < 4; ++rr){
            float mean = s[rr] * (1.0f / 128.0f);
            float var  = q[rr] * (1.0f / 128.0f) - mean * mean;
            float inv  = rsqrtf(var + LN_EPS);
            #pragma unroll
            for (int nt = 0; nt < 4; ++nt){
                int cf = nt * 16 + lr, cc = cf + 64;
                float zf = (acc2[nt][rr]     - mean) * inv * g2[cf] + be2[cf];
                float zc = (acc2[nt + 4][rr] - mean) * inv * g2[cc] + be2[cc];
                prod[w * 16 + lg * 4 + rr][cf] = sigmoidf_(zf) * softplusf_(zc);
            }
        }
    }
    __syncthreads();

    // epilogue 2 -> outF
    if (t < 64){
        int a_ = t >> 4, c0 = (t & 15) * 4;
        float4 sm = make_float4(0, 0, 0, 0);
        #pragma unroll
        for (int m = 0; m < 12; ++m){
            const float4 pv = *(const float4*)&prod[a_ * 12 + m][c0];
            sm.x += pv.x; sm.y += pv.y; sm.z += pv.z; sm.w += pv.w;
        }
        int atom = blk * 4 + a_;
        const float4 sf = *(const float4*)(&sSF[a_][c0]);
        float o0 = softplusf_(sf.x + sm.x);
        float o1 = softplusf_(sf.y + sm.y);
        float o2 = softplusf_(sf.z + sm.z);
        float o3 = softplusf_(sf.w + sm.w);
        *(float4*)(outF + (long)atom * 64 + c0) = make_float4(o0, o1, o2, o3);
    }
}

// ---------------- pooling: deterministic two-stage tree ----------------
__global__ __launch_bounds__(256) void k_partial(const float* __restrict__ atom,
        const float* __restrict__ occ, float* __restrict__ partials){
    int b = blockIdx.x, tid = threadIdx.x;
    int f = tid & 63, sub = tid >> 6;
    __shared__ float sAcc[256];
    float acc = 0.0f;
    for (int it = 0; it < 16; ++it){
        int a = b * 64 + sub + it * 4;
        float p = sigmoidf_(occ[a]);
        acc += atom[(long)a * FEA + f] * p;
    }
    sAcc[tid] = acc;
    __syncthreads();
    if (tid < 64){
        float s = sAcc[f] + sAcc[64 + f] + sAcc[128 + f] + sAcc[192 + f];
        partials[b * 65 + f] = s;
        float po = sigmoidf_(occ[b * 64 + f]);
        #pragma unroll
        for (int off = 32; off; off >>= 1) po += __shfl_down(po, off);
        if (f == 0) partials[b * 65 + 64] = po;
    }
}

__global__ __launch_bounds__(64) void k_final(const float* __restrict__ partials,
        const float* __restrict__ fc_w, const float* __restrict__ fc_b,
        float* __restrict__ out){
    int f = threadIdx.x;
    float num = 0.0f;
    for (int p = 0; p < 64; ++p) num += partials[p * 65 + f];
    float occs = partials[f * 65 + 64];
    #pragma unroll
    for (int off = 32; off; off >>= 1) occs += __shfl_down(occs, off);
    occs = __shfl(occs, 0);
    float gf = num / (occs + 1e-6f);
    float v = gf * fc_w[f];
    #pragma unroll
    for (int off = 32; off; off >>= 1) v += __shfl_down(v, off);
    if (f == 0) out[0] = v + fc_b[0];
}

extern "C" void kernel_launch(void* const* d_in, const int* in_sizes, int n_in,
                              void* d_out, int out_size, void* d_ws, size_t ws_size,
                              hipStream_t stream) {
    const float* lat    = (const float*)d_in[0];
    const float* fracs  = (const float*)d_in[1];
    const float* slog   = (const float*)d_in[2];
    const float* occ    = (const float*)d_in[3];
    const float* emb_w  = (const float*)d_in[4];
    const float* emb_b  = (const float*)d_in[5];
    const float* w1     = (const float*)d_in[6];
    const float* b1     = (const float*)d_in[7];
    const float* g1     = (const float*)d_in[8];
    const float* be1    = (const float*)d_in[9];
    const float* w2     = (const float*)d_in[10];
    const float* b2     = (const float*)d_in[11];
    const float* g2     = (const float*)d_in[12];
    const float* be2    = (const float*)d_in[13];
    const float* fc_w   = (const float*)d_in[14];
    const float* fc_b   = (const float*)d_in[15];
    float* out = (float*)d_out;

    char* ws = (char*)d_ws;
    auto alloc = [&](size_t bytes) -> void* {
        void* p = (void*)ws;
        ws += (bytes + 255) & ~(size_t)255;
        return p;
    };
    int*   nbr_idx  = (int*)  alloc((size_t)N_ATOMS * M_NBR * 4);
    float* nbr_dist = (float*)alloc((size_t)N_ATOMS * M_NBR * 4);
    float* atom0    = (float*)alloc((size_t)N_ATOMS * FEA * 4);
    float* atom1    = (float*)alloc((size_t)N_ATOMS * FEA * 4);
    u16*   a0f      = (u16*)  alloc((size_t)N_ATOMS * FEA * 2);
    u16*   wpk      = (u16*)  alloc((size_t)6 * 8192 * 2);
    float* S1       = (float*)alloc((size_t)N_ATOMS * 128 * 4);
    float* fxa      = (float*)alloc((size_t)N_ATOMS * 4);
    float* fya      = (float*)alloc((size_t)N_ATOMS * 4);
    float* fza      = (float*)alloc((size_t)N_ATOMS * 4);
    float* partials = (float*)alloc((size_t)64 * 65 * 4);

    k_setup  <<<208, 256, 0, stream>>>(fracs, w1, w2, fxa, fya, fza, wpk);
    k_embed  <<<N_ATOMS / 4, 256, 0, stream>>>(slog, emb_w, emb_b, atom0, a0f);
    k_topk   <<<N_ATOMS, 256, 0, stream>>>(fxa, fya, fza, lat, nbr_idx, nbr_dist);
    k_precomp<<<N_ATOMS / 16, 64, 0, stream>>>(a0f, wpk, b1, S1);
    k_fused  <<<N_ATOMS / 4, 192, 0, stream>>>(atom0, a0f, nbr_idx, nbr_dist, S1,
                wpk, g1, be1, b2, g2, be2, atom1);
    k_partial<<<64, 256, 0, stream>>>(atom1, occ, partials);
    k_final  <<<1, 64, 0, stream>>>(partials, fc_w, fc_b, out);
}

// Round 10
// 79.902 us; speedup vs baseline: 1.3688x; 1.2015x over previous
//
#include <hip/hip_runtime.h>
#include <math.h>

#define N_ATOMS 4096
#define SPECIES 100
#define FEA 64
#define M_NBR 12

typedef unsigned short u16;
typedef __attribute__((ext_vector_type(8))) _Float16 f16x8;
typedef __attribute__((ext_vector_type(4))) float f32x4;

constexpr float LN_EPS = 1e-5f;
constexpr float GAUSS_COEFF = -31.0078125f; // -0.5/(8/63)^2
constexpr float D2_INF = 3.4e38f;

// branch-free fast activations (v_exp_f32 / v_log_f32 / v_rcp_f32 based)
__device__ __forceinline__ float sigmoidf_(float x){
    return __fdividef(1.0f, 1.0f + __expf(-x));
}
__device__ __forceinline__ float softplusf_(float x){
    return fmaxf(x, 0.0f) + __logf(1.0f + __expf(-fabsf(x)));
}
__device__ __forceinline__ u16 f16bits(_Float16 h){ return *(u16*)&h; }

// ---------------- setup: fracs transpose + weight fp16 split-pack ----------------
// W[192][128] splits into 3 K=64 blocks: self(0-63), nbr(64-127), gauss(128-191).
// mat = layer*3 + k/64  (0:S1 1:N1 2:G1 3:S2 4:N2 5:G2), each 16KB fp16 in
// per-(ch,nt) wave-contiguous B layout: dest[mat*8192 + ((ch*8+nt)*64+lane)*8 + i]
__global__ __launch_bounds__(256) void k_setup(const float* __restrict__ fracs,
        const float* __restrict__ w1, const float* __restrict__ w2,
        float* __restrict__ fx, float* __restrict__ fy, float* __restrict__ fz,
        u16* __restrict__ wpk){
    int b = blockIdx.x, t = threadIdx.x;
    if (b < 192){
        int gid = b * 256 + t;             // 0..49151
        int layer = gid / 24576;
        int e = gid % 24576;
        int k = e >> 7, n = e & 127;
        float x = (layer ? w2 : w1)[e];
        int mat = layer * 3 + (k >> 6);
        int kk = k & 63;
        int ch = kk >> 5, lg2 = (kk >> 3) & 3, i = kk & 7;
        int nt = n >> 4, lr2 = n & 15;
        int dest = mat * 8192 + ((ch * 8 + nt) * 64 + (lg2 * 16 + lr2)) * 8 + i;
        wpk[dest] = f16bits((_Float16)x);
    } else {
        int j = (b - 192) * 256 + t;
        fx[j] = fracs[j*3+0];
        fy[j] = fracs[j*3+1];
        fz[j] = fracs[j*3+2];
    }
}

// ---------------- embedding: softmax(species_logits) @ emb_w + emb_b ----------------
__global__ __launch_bounds__(256) void k_embed(const float* __restrict__ logits,
        const float* __restrict__ emb_w, const float* __restrict__ emb_b,
        float* __restrict__ atom0, u16* __restrict__ a0f){
    __shared__ float sE[4][SPECIES];
    int tid = threadIdx.x;
    int grp = tid >> 6;
    int f = tid & 63;
    int a = blockIdx.x * 4 + grp;
    const float* lg = logits + (long)a * SPECIES;
    float l0 = lg[f];
    float l1 = (f + 64 < SPECIES) ? lg[f + 64] : -1e30f;
    float mx = fmaxf(l0, l1);
    #pragma unroll
    for (int off = 32; off; off >>= 1) mx = fmaxf(mx, __shfl_xor(mx, off));
    float e0 = __expf(l0 - mx);
    float e1 = (f + 64 < SPECIES) ? __expf(l1 - mx) : 0.0f;
    sE[grp][f] = e0;
    if (f + 64 < SPECIES) sE[grp][64 + f] = e1;
    float sm = e0 + e1;
    #pragma unroll
    for (int off = 32; off; off >>= 1) sm += __shfl_xor(sm, off);
    __syncthreads();
    float acc = 0.0f;
    for (int s = 0; s < SPECIES; ++s) acc += sE[grp][s] * emb_w[s * FEA + f];
    float v = acc / sm + emb_b[f];
    atom0[(long)a * FEA + f] = v;
    a0f[a * FEA + f] = f16bits((_Float16)v);
}

// ---------------- top-12 via histogram threshold + candidate compaction ----------------
__global__ __launch_bounds__(256) void k_topk(const float* __restrict__ fx,
        const float* __restrict__ fy, const float* __restrict__ fz,
        const float* __restrict__ lat, int* __restrict__ nbr_idx,
        float* __restrict__ nbr_dist){
    __shared__ int   hist[256];
    __shared__ int   cnt;
    __shared__ float sThr;
    __shared__ float candD[256];
    __shared__ int   candI[256];
    int i = blockIdx.x, tid = threadIdx.x;
    hist[tid] = 0;
    if (tid == 0) cnt = 0;
    __syncthreads();
    float l00=lat[0],l01=lat[1],l02=lat[2];
    float l10=lat[3],l11=lat[4],l12=lat[5];
    float l20=lat[6],l21=lat[7],l22=lat[8];
    float xi = fx[i], yi = fy[i], zi = fz[i];
    float d2r[16];
    #pragma unroll
    for (int k = 0; k < 16; ++k){
        int j = tid + k * 256;
        float dx = xi - fx[j];
        float dy = yi - fy[j];
        float dz = zi - fz[j];
        dx -= rintf(dx); dy -= rintf(dy); dz -= rintf(dz);
        float cx = dx*l00 + dy*l10 + dz*l20;
        float cy = dx*l01 + dy*l11 + dz*l21;
        float cz = dx*l02 + dy*l12 + dz*l22;
        float d2 = cx*cx + cy*cy + cz*cz;
        if (j == i) d2 = D2_INF;
        d2r[k] = d2;
        if (d2 < 4.0f) atomicAdd(&hist[(int)(d2 * 64.0f)], 1);
    }
    __syncthreads();
    if (tid < 64){
        int s0 = hist[4*tid] + hist[4*tid+1] + hist[4*tid+2] + hist[4*tid+3];
        int sc = s0;
        #pragma unroll
        for (int off = 1; off < 64; off <<= 1){
            int o = __shfl_up(sc, off);
            if (tid >= off) sc += o;
        }
        unsigned long long mball = __ballot(sc >= M_NBR);
        if (mball == 0ULL){
            if (tid == 0) sThr = 1e30f;
        } else {
            int gbin = __ffsll(mball) - 1;
            if (tid == gbin){
                int c = sc - s0;
                float th = 4.0f;
                #pragma unroll
                for (int b = 0; b < 4; ++b){
                    c += hist[4*gbin + b];
                    if (c >= M_NBR){ th = (float)(4*gbin + b + 1) * (1.0f/64.0f); break; }
                }
                sThr = th;
            }
        }
    }
    __syncthreads();
    float thr = sThr;
    #pragma unroll
    for (int k = 0; k < 16; ++k){
        if (d2r[k] < thr){
            int p = atomicAdd(&cnt, 1);
            if (p < 256){ candD[p] = d2r[k]; candI[p] = tid + k * 256; }
        }
    }
    __syncthreads();
    if (tid < 64){
        int n = cnt < 256 ? cnt : 256;
        float v0 = (tid       < n) ? candD[tid]       : D2_INF;
        int   i0 = (tid       < n) ? candI[tid]       : 0x7FFFFFFF;
        float v1 = (tid + 64  < n) ? candD[tid + 64]  : D2_INF;
        int   i1 = (tid + 64  < n) ? candI[tid + 64]  : 0x7FFFFFFF;
        float v2 = (tid + 128 < n) ? candD[tid + 128] : D2_INF;
        int   i2 = (tid + 128 < n) ? candI[tid + 128] : 0x7FFFFFFF;
        float v3 = (tid + 192 < n) ? candD[tid + 192] : D2_INF;
        int   i3 = (tid + 192 < n) ? candI[tid + 192] : 0x7FFFFFFF;
        for (int r = 0; r < M_NBR; ++r){
            float bv = v0; int bi = i0;
            if (v1 < bv || (v1 == bv && i1 < bi)){ bv = v1; bi = i1; }
            if (v2 < bv || (v2 == bv && i2 < bi)){ bv = v2; bi = i2; }
            if (v3 < bv || (v3 == bv && i3 < bi)){ bv = v3; bi = i3; }
            #pragma unroll
            for (int off = 1; off < 64; off <<= 1){
                float ov = __shfl_xor(bv, off);
                int   oi = __shfl_xor(bi, off);
                if (ov < bv || (ov == bv && oi < bi)){ bv = ov; bi = oi; }
            }
            if (i0 == bi) v0 = D2_INF;
            if (i1 == bi) v1 = D2_INF;
            if (i2 == bi) v2 = D2_INF;
            if (i3 == bi) v3 = D2_INF;
            if (tid == 0){
                nbr_idx[i * M_NBR + r]  = bi;
                nbr_dist[i * M_NBR + r] = sqrtf(bv);
            }
        }
    }
}

// ---------------- precompute S1 = a0f @ Ws1 + b1  (bias folded) ----------------
__global__ __launch_bounds__(64) void k_precomp(const u16* __restrict__ a0f,
        const u16* __restrict__ wpk, const float* __restrict__ b1,
        float* __restrict__ S1){
    const int l = threadIdx.x;
    const int lg = l >> 4, lr = l & 15;
    const int blk = blockIdx.x;
    f16x8 af[2];
    #pragma unroll
    for (int c = 0; c < 2; ++c)
        af[c] = *(const f16x8*)(a0f + (blk * 16 + lr) * 64 + c * 32 + lg * 8);
    f32x4 acc[8];
    #pragma unroll
    for (int nt = 0; nt < 8; ++nt) acc[nt] = 0.0f;
    #pragma unroll
    for (int c = 0; c < 2; ++c)
        #pragma unroll
        for (int nt = 0; nt < 8; ++nt){
            const f16x8 b = *(const f16x8*)(wpk + ((c * 8 + nt) * 64 + l) * 8);
            acc[nt] = __builtin_amdgcn_mfma_f32_16x16x32_f16(af[c], b, acc[nt], 0, 0, 0);
        }
    #pragma unroll
    for (int nt = 0; nt < 8; ++nt)
        #pragma unroll
        for (int rr = 0; rr < 4; ++rr)
            S1[(blk * 16 + lg * 4 + rr) * 128 + nt * 16 + lr] = acc[nt][rr] + b1[nt * 16 + lr];
}

// ---------------- fused CGCNN layers 1+2 ----------------
// Block = 192 thr (3 waves x 16 rows) = 48 rows = 4 atoms; grid 1024.
__global__ __launch_bounds__(192) void k_fused(
        const float* __restrict__ atom0F, const u16* __restrict__ a0f,
        const int* __restrict__ nbr_idx, const float* __restrict__ nbr_dist,
        const float* __restrict__ S1g, const u16* __restrict__ wpk,
        const float* __restrict__ g1, const float* __restrict__ be1,
        const float* __restrict__ b2, const float* __restrict__ g2,
        const float* __restrict__ be2, float* __restrict__ outF)
{
    __shared__ float sS1[4][132];    // S1 (+b1) for the block's 4 atoms
    __shared__ float prod[48][68];
    __shared__ float sSF[4][64];     // layer-1 out f32 (residual)
    __shared__ u16   sSH[4][64];     // layer-1 out fp16 (A-frags for S2)
    __shared__ float sS2[4][132];    // S2 (+b2)

    const int t = threadIdx.x;
    const int w = t >> 6, l = t & 63;
    const int lg = l >> 4, lr = l & 15;
    const int blk = blockIdx.x;
    const int row = blk * 48 + w * 16 + lr;

    // issue the random nbr gather ASAP (the only latency-critical loads)
    const int nid = nbr_idx[row];
    f16x8 nfr[2];
    nfr[0] = *(const f16x8*)(a0f + nid * 64 + lg * 8);
    nfr[1] = *(const f16x8*)(a0f + nid * 64 + 32 + lg * 8);

    // stage S1 rows for the 4 atoms (contiguous, L2-hot)
    if (t < 128){
        int a_ = t >> 5, c4 = (t & 31) << 2;
        *(float4*)(&sS1[a_][c4]) = *(const float4*)(S1g + (long)(blk * 4 + a_) * 128 + c4);
    }

    // preload gamma/beta for both layers (out of the dependent LN chain)
    float g1v[8], be1v[8], g2v[8], be2v[8];
    #pragma unroll
    for (int nt = 0; nt < 8; ++nt){
        int c = nt * 16 + lr;
        g1v[nt] = g1[c]; be1v[nt] = be1[c];
        g2v[nt] = g2[c]; be2v[nt] = be2[c];
    }

    // gaussian A-fragments (VALU work overlapping the gathers)
    const float dist = nbr_dist[row];
    f16x8 ga[2];
    #pragma unroll
    for (int c = 0; c < 2; ++c)
        #pragma unroll
        for (int i = 0; i < 8; ++i){
            int k = c * 32 + lg * 8 + i;
            float dd = dist - (float)k * (8.0f / 63.0f);
            ga[c][i] = (_Float16)__expf(GAUSS_COEFF * dd * dd);
        }

    // z-row -> local atom mapping (C rows: lg*4+rr)
    int aloc[4];
    #pragma unroll
    for (int rr = 0; rr < 4; ++rr)
        aloc[rr] = (w * 16 + lg * 4 + rr) / 12;

    const u16* wn1 = wpk + 1 * 8192;
    const u16* wg1 = wpk + 2 * 8192;
    const u16* ws2 = wpk + 3 * 8192;
    const u16* wn2 = wpk + 4 * 8192;
    const u16* wg2 = wpk + 5 * 8192;

    // ---- layer 1 MFMA: nbr + gauss ----
    f32x4 acc[8];
    #pragma unroll
    for (int nt = 0; nt < 8; ++nt) acc[nt] = 0.0f;
    #pragma unroll
    for (int c = 0; c < 2; ++c)
        #pragma unroll
        for (int nt = 0; nt < 8; ++nt){
            const f16x8 bn = *(const f16x8*)(wn1 + ((c * 8 + nt) * 64 + l) * 8);
            acc[nt] = __builtin_amdgcn_mfma_f32_16x16x32_f16(nfr[c], bn, acc[nt], 0, 0, 0);
            const f16x8 bg = *(const f16x8*)(wg1 + ((c * 8 + nt) * 64 + l) * 8);
            acc[nt] = __builtin_amdgcn_mfma_f32_16x16x32_f16(ga[c], bg, acc[nt], 0, 0, 0);
        }
    __syncthreads();   // sS1 staged

    // z1 = acc + S1(+b1); LN1; products
    {
        float s[4] = {0,0,0,0}, q[4] = {0,0,0,0};
        #pragma unroll
        for (int nt = 0; nt < 8; ++nt)
            #pragma unroll
            for (int rr = 0; rr < 4; ++rr){
                float v = acc[nt][rr] + sS1[aloc[rr]][nt * 16 + lr];
                acc[nt][rr] = v;
                s[rr] += v; q[rr] += v * v;
            }
        #pragma unroll
        for (int rr = 0; rr < 4; ++rr){
            #pragma unroll
            for (int m = 1; m < 16; m <<= 1){
                s[rr] += __shfl_xor(s[rr], m);
                q[rr] += __shfl_xor(q[rr], m);
            }
        }
        #pragma unroll
        for (int rr = 0; rr < 4; ++rr){
            float mean = s[rr] * (1.0f / 128.0f);
            float var  = q[rr] * (1.0f / 128.0f) - mean * mean;
            float inv  = rsqrtf(var + LN_EPS);
            #pragma unroll
            for (int nt = 0; nt < 4; ++nt){
                float zf = (acc[nt][rr]     - mean) * inv * g1v[nt]     + be1v[nt];
                float zc = (acc[nt + 4][rr] - mean) * inv * g1v[nt + 4] + be1v[nt + 4];
                prod[w * 16 + lg * 4 + rr][nt * 16 + lr] = sigmoidf_(zf) * softplusf_(zc);
            }
        }
    }
    __syncthreads();

    // epilogue 1: per-atom reduce 12 rows + residual + softplus -> sSF/sSH
    if (t < 64){
        int a_ = t >> 4, c0 = (t & 15) * 4;
        float4 sm = make_float4(0, 0, 0, 0);
        #pragma unroll
        for (int m = 0; m < 12; ++m){
            const float4 pv = *(const float4*)&prod[a_ * 12 + m][c0];
            sm.x += pv.x; sm.y += pv.y; sm.z += pv.z; sm.w += pv.w;
        }
        int atom = blk * 4 + a_;
        const float4 sf = *(const float4*)(atom0F + (long)atom * 64 + c0);
        float o0 = softplusf_(sf.x + sm.x);
        float o1 = softplusf_(sf.y + sm.y);
        float o2 = softplusf_(sf.z + sm.z);
        float o3 = softplusf_(sf.w + sm.w);
        *(float4*)(&sSF[a_][c0]) = make_float4(o0, o1, o2, o3);
        ushort4 hv;
        hv.x = f16bits((_Float16)o0); hv.y = f16bits((_Float16)o1);
        hv.z = f16bits((_Float16)o2); hv.w = f16bits((_Float16)o3);
        *(ushort4*)(&sSH[a_][c0]) = hv;
    }
    __syncthreads();

    // S2 mini-GEMM (wave 0): sS2[a][c] = atom1[a][:] @ Ws2 + b2[c]
    if (t < 64){
        f16x8 af[2];
        #pragma unroll
        for (int c = 0; c < 2; ++c){
            if (lr < 4) af[c] = *(const f16x8*)(&sSH[lr][c * 32 + lg * 8]);
            else        af[c] = 0;
        }
        f32x4 a2[8];
        #pragma unroll
        for (int nt = 0; nt < 8; ++nt) a2[nt] = 0.0f;
        #pragma unroll
        for (int c = 0; c < 2; ++c)
            #pragma unroll
            for (int nt = 0; nt < 8; ++nt){
                const f16x8 b = *(const f16x8*)(ws2 + ((c * 8 + nt) * 64 + l) * 8);
                a2[nt] = __builtin_amdgcn_mfma_f32_16x16x32_f16(af[c], b, a2[nt], 0, 0, 0);
            }
        if (lg == 0){
            #pragma unroll
            for (int nt = 0; nt < 8; ++nt)
                #pragma unroll
                for (int rr = 0; rr < 4; ++rr)
                    sS2[rr][nt * 16 + lr] = a2[nt][rr] + b2[nt * 16 + lr];
        }
    }

    // ---- layer 2 MFMA: nbr + gauss (fragments reused, B swapped) ----
    f32x4 acc2[8];
    #pragma unroll
    for (int nt = 0; nt < 8; ++nt) acc2[nt] = 0.0f;
    #pragma unroll
    for (int c = 0; c < 2; ++c)
        #pragma unroll
        for (int nt = 0; nt < 8; ++nt){
            const f16x8 bn = *(const f16x8*)(wn2 + ((c * 8 + nt) * 64 + l) * 8);
            acc2[nt] = __builtin_amdgcn_mfma_f32_16x16x32_f16(nfr[c], bn, acc2[nt], 0, 0, 0);
            const f16x8 bg = *(const f16x8*)(wg2 + ((c * 8 + nt) * 64 + l) * 8);
            acc2[nt] = __builtin_amdgcn_mfma_f32_16x16x32_f16(ga[c], bg, acc2[nt], 0, 0, 0);
        }
    __syncthreads();   // sS2 ready

    // z2 = acc2 + S2(+b2); LN2; products
    {
        float s[4] = {0,0,0,0}, q[4] = {0,0,0,0};
        #pragma unroll
        for (int nt = 0; nt < 8; ++nt)
            #pragma unroll
            for (int rr = 0; rr < 4; ++rr){
                float v = acc2[nt][rr] + sS2[aloc[rr]][nt * 16 + lr];
                acc2[nt][rr] = v;
                s[rr] += v; q[rr] += v * v;
            }
        #pragma unroll
        for (int rr = 0; rr < 4; ++rr){
            #pragma unroll
            for (int m = 1; m < 16; m <<= 1){
                s[rr] += __shfl_xor(s[rr], m);
                q[rr] += __shfl_xor(q[rr], m);
            }
        }
        #pragma unroll
        for (int rr = 0; rr < 4; ++rr){
            float mean = s[rr] * (1.0f / 128.0f);
            float var  = q[rr] * (1.0f / 128.0f) - mean * mean;
            float inv  = rsqrtf(var + LN_EPS);
            #pragma unroll
            for (int nt = 0; nt < 4; ++nt){
                float zf = (acc2[nt][rr]     - mean) * inv * g2v[nt]     + be2v[nt];
                float zc = (acc2[nt + 4][rr] - mean) * inv * g2v[nt + 4] + be2v[nt + 4];
                prod[w * 16 + lg * 4 + rr][nt * 16 + lr] = sigmoidf_(zf) * softplusf_(zc);
            }
        }
    }
    __syncthreads();

    // epilogue 2 -> outF
    if (t < 64){
        int a_ = t >> 4, c0 = (t & 15) * 4;
        float4 sm = make_float4(0, 0, 0, 0);
        #pragma unroll
        for (int m = 0; m < 12; ++m){
            const float4 pv = *(const float4*)&prod[a_ * 12 + m][c0];
            sm.x += pv.x; sm.y += pv.y; sm.z += pv.z; sm.w += pv.w;
        }
        int atom = blk * 4 + a_;
        const float4 sf = *(const float4*)(&sSF[a_][c0]);
        float o0 = softplusf_(sf.x + sm.x);
        float o1 = softplusf_(sf.y + sm.y);
        float o2 = softplusf_(sf.z + sm.z);
        float o3 = softplusf_(sf.w + sm.w);
        *(float4*)(outF + (long)atom * 64 + c0) = make_float4(o0, o1, o2, o3);
    }
}

// ---------------- pooling: deterministic two-stage tree ----------------
__global__ __launch_bounds__(256) void k_partial(const float* __restrict__ atom,
        const float* __restrict__ occ, float* __restrict__ partials){
    int b = blockIdx.x, tid = threadIdx.x;
    int f = tid & 63, sub = tid >> 6;
    __shared__ float sAcc[256];
    float acc = 0.0f;
    for (int it = 0; it < 16; ++it){
        int a = b * 64 + sub + it * 4;
        float p = sigmoidf_(occ[a]);
        acc += atom[(long)a * FEA + f] * p;
    }
    sAcc[tid] = acc;
    __syncthreads();
    if (tid < 64){
        float s = sAcc[f] + sAcc[64 + f] + sAcc[128 + f] + sAcc[192 + f];
        partials[b * 65 + f] = s;
        float po = sigmoidf_(occ[b * 64 + f]);
        #pragma unroll
        for (int off = 32; off; off >>= 1) po += __shfl_down(po, off);
        if (f == 0) partials[b * 65 + 64] = po;
    }
}

__global__ __launch_bounds__(64) void k_final(const float* __restrict__ partials,
        const float* __restrict__ fc_w, const float* __restrict__ fc_b,
        float* __restrict__ out){
    int f = threadIdx.x;
    float num = 0.0f;
    for (int p = 0; p < 64; ++p) num += partials[p * 65 + f];
    float occs = partials[f * 65 + 64];
    #pragma unroll
    for (int off = 32; off; off >>= 1) occs += __shfl_down(occs, off);
    occs = __shfl(occs, 0);
    float gf = num / (occs + 1e-6f);
    float v = gf * fc_w[f];
    #pragma unroll
    for (int off = 32; off; off >>= 1) v += __shfl_down(v, off);
    if (f == 0) out[0] = v + fc_b[0];
}

extern "C" void kernel_launch(void* const* d_in, const int* in_sizes, int n_in,
                              void* d_out, int out_size, void* d_ws, size_t ws_size,
                              hipStream_t stream) {
    const float* lat    = (const float*)d_in[0];
    const float* fracs  = (const float*)d_in[1];
    const float* slog   = (const float*)d_in[2];
    const float* occ    = (const float*)d_in[3];
    const float* emb_w  = (const float*)d_in[4];
    const float* emb_b  = (const float*)d_in[5];
    const float* w1     = (const float*)d_in[6];
    const float* b1     = (const float*)d_in[7];
    const float* g1     = (const float*)d_in[8];
    const float* be1    = (const float*)d_in[9];
    const float* w2     = (const float*)d_in[10];
    const float* b2     = (const float*)d_in[11];
    const float* g2     = (const float*)d_in[12];
    const float* be2    = (const float*)d_in[13];
    const float* fc_w   = (const float*)d_in[14];
    const float* fc_b   = (const float*)d_in[15];
    float* out = (float*)d_out;

    char* ws = (char*)d_ws;
    auto alloc = [&](size_t bytes) -> void* {
        void* p = (void*)ws;
        ws += (bytes + 255) & ~(size_t)255;
        return p;
    };
    int*   nbr_idx  = (int*)  alloc((size_t)N_ATOMS * M_NBR * 4);
    float* nbr_dist = (float*)alloc((size_t)N_ATOMS * M_NBR * 4);
    float* atom0    = (float*)alloc((size_t)N_ATOMS * FEA * 4);
    float* atom1    = (float*)alloc((size_t)N_ATOMS * FEA * 4);
    u16*   a0f      = (u16*)  alloc((size_t)N_ATOMS * FEA * 2);
    u16*   wpk      = (u16*)  alloc((size_t)6 * 8192 * 2);
    float* S1       = (float*)alloc((size_t)N_ATOMS * 128 * 4);
    float* fxa      = (float*)alloc((size_t)N_ATOMS * 4);
    float* fya      = (float*)alloc((size_t)N_ATOMS * 4);
    float* fza      = (float*)alloc((size_t)N_ATOMS * 4);
    float* partials = (float*)alloc((size_t)64 * 65 * 4);

    k_setup  <<<208, 256, 0, stream>>>(fracs, w1, w2, fxa, fya, fza, wpk);
    k_embed  <<<N_ATOMS / 4, 256, 0, stream>>>(slog, emb_w, emb_b, atom0, a0f);
    k_topk   <<<N_ATOMS, 256, 0, stream>>>(fxa, fya, fza, lat, nbr_idx, nbr_dist);
    k_precomp<<<N_ATOMS / 16, 64, 0, stream>>>(a0f, wpk, b1, S1);
    k_fused  <<<N_ATOMS / 4, 192, 0, stream>>>(atom0, a0f, nbr_idx, nbr_dist, S1,
                wpk, g1, be1, b2, g2, be2, atom1);
    k_partial<<<64, 256, 0, stream>>>(atom1, occ, partials);
    k_final  <<<1, 64, 0, stream>>>(partials, fc_w, fc_b, out);
}

// Round 11
// 62.110 us; speedup vs baseline: 1.7609x; 1.2865x over previous
//
#include <hip/hip_runtime.h>
#include <math.h>

#define N_ATOMS 4096
#define SPECIES 100
#define FEA 64
#define M_NBR 12

typedef unsigned short u16;
typedef __attribute__((ext_vector_type(8))) _Float16 f16x8;
typedef __attribute__((ext_vector_type(4))) float f32x4;

constexpr float LN_EPS = 1e-5f;
constexpr float GAUSS_COEFF = -31.0078125f; // -0.5/(8/63)^2
constexpr float D2_INF = 3.4e38f;

__device__ __forceinline__ float sigmoidf_(float x){
    return __fdividef(1.0f, 1.0f + __expf(-x));
}
__device__ __forceinline__ float softplusf_(float x){
    return fmaxf(x, 0.0f) + __logf(1.0f + __expf(-fabsf(x)));
}
__device__ __forceinline__ u16 f16bits(_Float16 h){ return *(u16*)&h; }

// ---------------- setup: wpk pack + fracs transpose + embedding, one launch ----------------
// wpk: W[192][128] -> 6 mats (S1,N1,G1,S2,N2,G2) of 16KB fp16 in per-(ch,nt)
// wave-contiguous B layout: dest[mat*8192 + ((ch*8+nt)*64+lane)*8 + i]
__global__ __launch_bounds__(256) void k_setup(const float* __restrict__ fracs,
        const float* __restrict__ w1, const float* __restrict__ w2,
        const float* __restrict__ logits, const float* __restrict__ emb_w,
        const float* __restrict__ emb_b,
        float* __restrict__ fx, float* __restrict__ fy, float* __restrict__ fz,
        u16* __restrict__ wpk, float* __restrict__ atom0, u16* __restrict__ a0f){
    __shared__ float sE[4][SPECIES];
    int b = blockIdx.x, t = threadIdx.x;
    if (b < 192){
        int gid = b * 256 + t;
        int layer = gid / 24576;
        int e = gid % 24576;
        int k = e >> 7, n = e & 127;
        float x = (layer ? w2 : w1)[e];
        int mat = layer * 3 + (k >> 6);
        int kk = k & 63;
        int ch = kk >> 5, lg2 = (kk >> 3) & 3, i = kk & 7;
        int nt = n >> 4, lr2 = n & 15;
        wpk[mat * 8192 + ((ch * 8 + nt) * 64 + (lg2 * 16 + lr2)) * 8 + i] = f16bits((_Float16)x);
    } else if (b < 208){
        int j = (b - 192) * 256 + t;
        fx[j] = fracs[j*3+0];
        fy[j] = fracs[j*3+1];
        fz[j] = fracs[j*3+2];
    } else {
        int grp = t >> 6, f = t & 63;
        int a = (b - 208) * 4 + grp;
        const float* lg = logits + (long)a * SPECIES;
        float l0 = lg[f];
        float l1 = (f + 64 < SPECIES) ? lg[f + 64] : -1e30f;
        float mx = fmaxf(l0, l1);
        #pragma unroll
        for (int off = 32; off; off >>= 1) mx = fmaxf(mx, __shfl_xor(mx, off));
        float e0 = __expf(l0 - mx);
        float e1 = (f + 64 < SPECIES) ? __expf(l1 - mx) : 0.0f;
        sE[grp][f] = e0;
        if (f + 64 < SPECIES) sE[grp][64 + f] = e1;
        float sm = e0 + e1;
        #pragma unroll
        for (int off = 32; off; off >>= 1) sm += __shfl_xor(sm, off);
        __syncthreads();
        float acc = 0.0f;
        for (int s = 0; s < SPECIES; ++s) acc += sE[grp][s] * emb_w[s * FEA + f];
        float v = acc / sm + emb_b[f];
        atom0[(long)a * FEA + f] = v;
        a0f[a * FEA + f] = f16bits((_Float16)v);
    }
}

// ---------------- top-12: histogram threshold + compaction + PARALLEL rank select ----------------
__global__ __launch_bounds__(256) void k_topk(const float* __restrict__ fx,
        const float* __restrict__ fy, const float* __restrict__ fz,
        const float* __restrict__ lat, int* __restrict__ nbr_idx,
        float* __restrict__ nbr_dist){
    __shared__ int   hist[256];
    __shared__ int   cnt;
    __shared__ float sThr;
    __shared__ float candD[256];
    __shared__ int   candI[256];
    int i = blockIdx.x, tid = threadIdx.x;
    hist[tid] = 0;
    if (tid == 0) cnt = 0;
    __syncthreads();
    float l00=lat[0],l01=lat[1],l02=lat[2];
    float l10=lat[3],l11=lat[4],l12=lat[5];
    float l20=lat[6],l21=lat[7],l22=lat[8];
    float xi = fx[i], yi = fy[i], zi = fz[i];
    float d2r[16];
    #pragma unroll
    for (int k = 0; k < 16; ++k){
        int j = tid + k * 256;
        float dx = xi - fx[j];
        float dy = yi - fy[j];
        float dz = zi - fz[j];
        dx -= rintf(dx); dy -= rintf(dy); dz -= rintf(dz);
        float cx = dx*l00 + dy*l10 + dz*l20;
        float cy = dx*l01 + dy*l11 + dz*l21;
        float cz = dx*l02 + dy*l12 + dz*l22;
        float d2 = cx*cx + cy*cy + cz*cz;
        if (j == i) d2 = D2_INF;
        d2r[k] = d2;
        if (d2 < 4.0f) atomicAdd(&hist[(int)(d2 * 64.0f)], 1);
    }
    __syncthreads();
    if (tid < 64){
        int s0 = hist[4*tid] + hist[4*tid+1] + hist[4*tid+2] + hist[4*tid+3];
        int sc = s0;
        #pragma unroll
        for (int off = 1; off < 64; off <<= 1){
            int o = __shfl_up(sc, off);
            if (tid >= off) sc += o;
        }
        unsigned long long mball = __ballot(sc >= M_NBR);
        if (mball == 0ULL){
            if (tid == 0) sThr = 1e30f;
        } else {
            int gbin = __ffsll(mball) - 1;
            if (tid == gbin){
                int c = sc - s0;
                float th = 4.0f;
                #pragma unroll
                for (int b = 0; b < 4; ++b){
                    c += hist[4*gbin + b];
                    if (c >= M_NBR){ th = (float)(4*gbin + b + 1) * (1.0f/64.0f); break; }
                }
                sThr = th;
            }
        }
    }
    __syncthreads();
    float thr = sThr;
    #pragma unroll
    for (int k = 0; k < 16; ++k){
        if (d2r[k] < thr){
            int p = atomicAdd(&cnt, 1);
            if (p < 256){ candD[p] = d2r[k]; candI[p] = tid + k * 256; }
        }
    }
    __syncthreads();
    // parallel rank selection: rank = #{smaller (d2, idx)}; rank<12 writes slot `rank`
    int n = cnt < 256 ? cnt : 256;
    for (int c = tid; c < n; c += 256){
        float dv = candD[c]; int iv = candI[c];
        int rank = 0;
        for (int s = 0; s < n; ++s){
            float ds_ = candD[s]; int is_ = candI[s];
            rank += (ds_ < dv || (ds_ == dv && is_ < iv)) ? 1 : 0;
        }
        if (rank < M_NBR){
            nbr_idx[i * M_NBR + rank]  = iv;
            nbr_dist[i * M_NBR + rank] = sqrtf(dv);
        }
    }
}

// ---------------- fused CGCNN layers 1+2, self-GEMMs in-block ----------------
// Block = 192 thr (3 waves x 16 rows) = 48 rows = 4 atoms; grid 1024.
// Wave1 computes S1 = a0f[4 atoms]@Ws1+b1 in-block (no cross-XCD S1 traffic).
// Both layers' edge-MFMAs issued back-to-back up front; epilogues parallel over 192 thr.
__global__ __launch_bounds__(192) void k_fused(
        const float* __restrict__ atom0F, const u16* __restrict__ a0f,
        const int* __restrict__ nbr_idx, const float* __restrict__ nbr_dist,
        const u16* __restrict__ wpk,
        const float* __restrict__ b1, const float* __restrict__ g1, const float* __restrict__ be1,
        const float* __restrict__ b2, const float* __restrict__ g2, const float* __restrict__ be2,
        float* __restrict__ outF)
{
    __shared__ float sS1[4][132];    // S1 (+b1)
    __shared__ float prod[48][68];
    __shared__ float sSF[4][64];     // layer-1 out f32 (residual)
    __shared__ u16   sSH[4][64];     // layer-1 out fp16 (A-frags for S2)
    __shared__ float sS2[4][132];    // S2 (+b2)

    const int t = threadIdx.x;
    const int w = t >> 6, l = t & 63;
    const int lg = l >> 4, lr = l & 15;
    const int blk = blockIdx.x;
    const int row = blk * 48 + w * 16 + lr;

    // latency-critical random gather first
    const int nid = nbr_idx[row];
    f16x8 nfr[2];
    nfr[0] = *(const f16x8*)(a0f + nid * 64 + lg * 8);
    nfr[1] = *(const f16x8*)(a0f + nid * 64 + 32 + lg * 8);

    // wave 1: self-atom A-frags (contiguous 512B) for the S1 mini-GEMM
    f16x8 saf[2];
    if (w == 1){
        #pragma unroll
        for (int c = 0; c < 2; ++c)
            saf[c] = (lr < 4) ? *(const f16x8*)(a0f + (blk * 4 + lr) * 64 + c * 32 + lg * 8)
                              : (f16x8)0;
    }

    // preload gamma/beta for both layers
    float g1v[8], be1v[8], g2v[8], be2v[8];
    #pragma unroll
    for (int nt = 0; nt < 8; ++nt){
        int c = nt * 16 + lr;
        g1v[nt] = g1[c]; be1v[nt] = be1[c];
        g2v[nt] = g2[c]; be2v[nt] = be2[c];
    }

    // gaussian A-fragments (shared by both layers)
    const float dist = nbr_dist[row];
    f16x8 ga[2];
    #pragma unroll
    for (int c = 0; c < 2; ++c)
        #pragma unroll
        for (int i = 0; i < 8; ++i){
            int k = c * 32 + lg * 8 + i;
            float dd = dist - (float)k * (8.0f / 63.0f);
            ga[c][i] = (_Float16)__expf(GAUSS_COEFF * dd * dd);
        }

    int aloc[4];
    #pragma unroll
    for (int rr = 0; rr < 4; ++rr)
        aloc[rr] = (w * 16 + lg * 4 + rr) / 12;

    const u16* ws1 = wpk;
    const u16* wn1 = wpk + 1 * 8192;
    const u16* wg1 = wpk + 2 * 8192;
    const u16* ws2 = wpk + 3 * 8192;
    const u16* wn2 = wpk + 4 * 8192;
    const u16* wg2 = wpk + 5 * 8192;

    // wave 1: S1 mini-GEMM -> sS1 (+b1)
    if (w == 1){
        f32x4 a1[8];
        #pragma unroll
        for (int nt = 0; nt < 8; ++nt) a1[nt] = 0.0f;
        #pragma unroll
        for (int c = 0; c < 2; ++c)
            #pragma unroll
            for (int nt = 0; nt < 8; ++nt){
                const f16x8 b = *(const f16x8*)(ws1 + ((c * 8 + nt) * 64 + l) * 8);
                a1[nt] = __builtin_amdgcn_mfma_f32_16x16x32_f16(saf[c], b, a1[nt], 0, 0, 0);
            }
        if (lg == 0){
            #pragma unroll
            for (int nt = 0; nt < 8; ++nt)
                #pragma unroll
                for (int rr = 0; rr < 4; ++rr)
                    sS1[rr][nt * 16 + lr] = a1[nt][rr] + b1[nt * 16 + lr];
        }
    }

    // layer-1 and layer-2 edge MFMAs back-to-back (both depend only on nfr/ga)
    f32x4 acc[8], acc2[8];
    #pragma unroll
    for (int nt = 0; nt < 8; ++nt){ acc[nt] = 0.0f; acc2[nt] = 0.0f; }
    #pragma unroll
    for (int c = 0; c < 2; ++c)
        #pragma unroll
        for (int nt = 0; nt < 8; ++nt){
            const f16x8 bn1 = *(const f16x8*)(wn1 + ((c * 8 + nt) * 64 + l) * 8);
            acc[nt]  = __builtin_amdgcn_mfma_f32_16x16x32_f16(nfr[c], bn1, acc[nt], 0, 0, 0);
            const f16x8 bg1 = *(const f16x8*)(wg1 + ((c * 8 + nt) * 64 + l) * 8);
            acc[nt]  = __builtin_amdgcn_mfma_f32_16x16x32_f16(ga[c],  bg1, acc[nt], 0, 0, 0);
            const f16x8 bn2 = *(const f16x8*)(wn2 + ((c * 8 + nt) * 64 + l) * 8);
            acc2[nt] = __builtin_amdgcn_mfma_f32_16x16x32_f16(nfr[c], bn2, acc2[nt], 0, 0, 0);
            const f16x8 bg2 = *(const f16x8*)(wg2 + ((c * 8 + nt) * 64 + l) * 8);
            acc2[nt] = __builtin_amdgcn_mfma_f32_16x16x32_f16(ga[c],  bg2, acc2[nt], 0, 0, 0);
        }
    __syncthreads();   // sS1 ready

    // z1 = acc + S1(+b1); LN1; products
    {
        float s[4] = {0,0,0,0}, q[4] = {0,0,0,0};
        #pragma unroll
        for (int nt = 0; nt < 8; ++nt)
            #pragma unroll
            for (int rr = 0; rr < 4; ++rr){
                float v = acc[nt][rr] + sS1[aloc[rr]][nt * 16 + lr];
                acc[nt][rr] = v;
                s[rr] += v; q[rr] += v * v;
            }
        #pragma unroll
        for (int rr = 0; rr < 4; ++rr){
            #pragma unroll
            for (int m = 1; m < 16; m <<= 1){
                s[rr] += __shfl_xor(s[rr], m);
                q[rr] += __shfl_xor(q[rr], m);
            }
        }
        #pragma unroll
        for (int rr = 0; rr < 4; ++rr){
            float mean = s[rr] * (1.0f / 128.0f);
            float var  = q[rr] * (1.0f / 128.0f) - mean * mean;
            float inv  = rsqrtf(var + LN_EPS);
            #pragma unroll
            for (int nt = 0; nt < 4; ++nt){
                float zf = (acc[nt][rr]     - mean) * inv * g1v[nt]     + be1v[nt];
                float zc = (acc[nt + 4][rr] - mean) * inv * g1v[nt + 4] + be1v[nt + 4];
                prod[w * 16 + lg * 4 + rr][nt * 16 + lr] = sigmoidf_(zf) * softplusf_(zc);
            }
        }
    }
    __syncthreads();

    // epilogue 1 (all 192 threads over 256 items): reduce 12 rows + residual + softplus
    #pragma unroll
    for (int rep = 0; rep < 2; ++rep){
        int item = t + rep * 192;
        if (item < 256){
            int a_ = item >> 6, c = item & 63;
            float sm = 0.0f;
            #pragma unroll
            for (int m = 0; m < 12; ++m) sm += prod[a_ * 12 + m][c];
            float o = softplusf_(atom0F[(long)(blk * 4 + a_) * 64 + c] + sm);
            sSF[a_][c] = o;
            sSH[a_][c] = f16bits((_Float16)o);
        }
    }
    __syncthreads();

    // S2 mini-GEMM (wave 0): sS2[a][c] = atom1[a][:] @ Ws2 + b2[c]
    if (w == 0){
        f16x8 af[2];
        #pragma unroll
        for (int c = 0; c < 2; ++c)
            af[c] = (lr < 4) ? *(const f16x8*)(&sSH[lr][c * 32 + lg * 8]) : (f16x8)0;
        f32x4 a2[8];
        #pragma unroll
        for (int nt = 0; nt < 8; ++nt) a2[nt] = 0.0f;
        #pragma unroll
        for (int c = 0; c < 2; ++c)
            #pragma unroll
            for (int nt = 0; nt < 8; ++nt){
                const f16x8 b = *(const f16x8*)(ws2 + ((c * 8 + nt) * 64 + l) * 8);
                a2[nt] = __builtin_amdgcn_mfma_f32_16x16x32_f16(af[c], b, a2[nt], 0, 0, 0);
            }
        if (lg == 0){
            #pragma unroll
            for (int nt = 0; nt < 8; ++nt)
                #pragma unroll
                for (int rr = 0; rr < 4; ++rr)
                    sS2[rr][nt * 16 + lr] = a2[nt][rr] + b2[nt * 16 + lr];
        }
    }
    __syncthreads();

    // z2 = acc2 + S2(+b2); LN2; products
    {
        float s[4] = {0,0,0,0}, q[4] = {0,0,0,0};
        #pragma unroll
        for (int nt = 0; nt < 8; ++nt)
            #pragma unroll
            for (int rr = 0; rr < 4; ++rr){
                float v = acc2[nt][rr] + sS2[aloc[rr]][nt * 16 + lr];
                acc2[nt][rr] = v;
                s[rr] += v; q[rr] += v * v;
            }
        #pragma unroll
        for (int rr = 0; rr < 4; ++rr){
            #pragma unroll
            for (int m = 1; m < 16; m <<= 1){
                s[rr] += __shfl_xor(s[rr], m);
                q[rr] += __shfl_xor(q[rr], m);
            }
        }
        #pragma unroll
        for (int rr = 0; rr < 4; ++rr){
            float mean = s[rr] * (1.0f / 128.0f);
            float var  = q[rr] * (1.0f / 128.0f) - mean * mean;
            float inv  = rsqrtf(var + LN_EPS);
            #pragma unroll
            for (int nt = 0; nt < 4; ++nt){
                float zf = (acc2[nt][rr]     - mean) * inv * g2v[nt]     + be2v[nt];
                float zc = (acc2[nt + 4][rr] - mean) * inv * g2v[nt + 4] + be2v[nt + 4];
                prod[w * 16 + lg * 4 + rr][nt * 16 + lr] = sigmoidf_(zf) * softplusf_(zc);
            }
        }
    }
    __syncthreads();

    // epilogue 2 (all 192 threads) -> outF
    #pragma unroll
    for (int rep = 0; rep < 2; ++rep){
        int item = t + rep * 192;
        if (item < 256){
            int a_ = item >> 6, c = item & 63;
            float sm = 0.0f;
            #pragma unroll
            for (int m = 0; m < 12; ++m) sm += prod[a_ * 12 + m][c];
            outF[(long)(blk * 4 + a_) * 64 + c] = softplusf_(sSF[a_][c] + sm);
        }
    }
}

// ---------------- pooling: deterministic two-stage tree ----------------
__global__ __launch_bounds__(256) void k_partial(const float* __restrict__ atom,
        const float* __restrict__ occ, float* __restrict__ partials){
    int b = blockIdx.x, tid = threadIdx.x;
    int f = tid & 63, sub = tid >> 6;
    __shared__ float sAcc[256];
    float acc = 0.0f;
    for (int it = 0; it < 16; ++it){
        int a = b * 64 + sub + it * 4;
        float p = sigmoidf_(occ[a]);
        acc += atom[(long)a * FEA + f] * p;
    }
    sAcc[tid] = acc;
    __syncthreads();
    if (tid < 64){
        float s = sAcc[f] + sAcc[64 + f] + sAcc[128 + f] + sAcc[192 + f];
        partials[b * 65 + f] = s;
        float po = sigmoidf_(occ[b * 64 + f]);
        #pragma unroll
        for (int off = 32; off; off >>= 1) po += __shfl_down(po, off);
        if (f == 0) partials[b * 65 + 64] = po;
    }
}

__global__ __launch_bounds__(64) void k_final(const float* __restrict__ partials,
        const float* __restrict__ fc_w, const float* __restrict__ fc_b,
        float* __restrict__ out){
    int f = threadIdx.x;
    float num = 0.0f;
    for (int p = 0; p < 64; ++p) num += partials[p * 65 + f];
    float occs = partials[f * 65 + 64];
    #pragma unroll
    for (int off = 32; off; off >>= 1) occs += __shfl_down(occs, off);
    occs = __shfl(occs, 0);
    float gf = num / (occs + 1e-6f);
    float v = gf * fc_w[f];
    #pragma unroll
    for (int off = 32; off; off >>= 1) v += __shfl_down(v, off);
    if (f == 0) out[0] = v + fc_b[0];
}

extern "C" void kernel_launch(void* const* d_in, const int* in_sizes, int n_in,
                              void* d_out, int out_size, void* d_ws, size_t ws_size,
                              hipStream_t stream) {
    const float* lat    = (const float*)d_in[0];
    const float* fracs  = (const float*)d_in[1];
    const float* slog   = (const float*)d_in[2];
    const float* occ    = (const float*)d_in[3];
    const float* emb_w  = (const float*)d_in[4];
    const float* emb_b  = (const float*)d_in[5];
    const float* w1     = (const float*)d_in[6];
    const float* b1     = (const float*)d_in[7];
    const float* g1     = (const float*)d_in[8];
    const float* be1    = (const float*)d_in[9];
    const float* w2     = (const float*)d_in[10];
    const float* b2     = (const float*)d_in[11];
    const float* g2     = (const float*)d_in[12];
    const float* be2    = (const float*)d_in[13];
    const float* fc_w   = (const float*)d_in[14];
    const float* fc_b   = (const float*)d_in[15];
    float* out = (float*)d_out;

    char* ws = (char*)d_ws;
    auto alloc = [&](size_t bytes) -> void* {
        void* p = (void*)ws;
        ws += (bytes + 255) & ~(size_t)255;
        return p;
    };
    int*   nbr_idx  = (int*)  alloc((size_t)N_ATOMS * M_NBR * 4);
    float* nbr_dist = (float*)alloc((size_t)N_ATOMS * M_NBR * 4);
    float* atom0    = (float*)alloc((size_t)N_ATOMS * FEA * 4);
    float* atom1    = (float*)alloc((size_t)N_ATOMS * FEA * 4);
    u16*   a0f      = (u16*)  alloc((size_t)N_ATOMS * FEA * 2);
    u16*   wpk      = (u16*)  alloc((size_t)6 * 8192 * 2);
    float* fxa      = (float*)alloc((size_t)N_ATOMS * 4);
    float* fya      = (float*)alloc((size_t)N_ATOMS * 4);
    float* fza      = (float*)alloc((size_t)N_ATOMS * 4);
    float* partials = (float*)alloc((size_t)64 * 65 * 4);

    k_setup  <<<208 + N_ATOMS / 4, 256, 0, stream>>>(fracs, w1, w2, slog, emb_w, emb_b,
                fxa, fya, fza, wpk, atom0, a0f);
    k_topk   <<<N_ATOMS, 256, 0, stream>>>(fxa, fya, fza, lat, nbr_idx, nbr_dist);
    k_fused  <<<N_ATOMS / 4, 192, 0, stream>>>(atom0, a0f, nbr_idx, nbr_dist,
                wpk, b1, g1, be1, b2, g2, be2, atom1);
    k_partial<<<64, 256, 0, stream>>>(atom1, occ, partials);
    k_final  <<<1, 64, 0, stream>>>(partials, fc_w, fc_b, out);
}